// Round 6
// baseline (410.371 us; speedup 1.0000x reference)
//
#include <hip/hip_runtime.h>
#include <stdint.h>

#define NTOK 65536     // B*S = 16*4096
#define DMODEL 512
#define QKVN 1536
#define LN_EPS 1e-5f

typedef __attribute__((ext_vector_type(8))) short short8;
typedef __attribute__((ext_vector_type(8))) unsigned short ushort8;
typedef __attribute__((ext_vector_type(4))) float float4_t;
typedef __attribute__((ext_vector_type(4))) unsigned int uint4_t;

static __device__ __forceinline__ float bf2f(unsigned short u) {
    union { unsigned int i; float f; } c; c.i = ((unsigned int)u) << 16; return c.f;
}
static __device__ __forceinline__ unsigned short f2bf(float f) {
    union { float f; unsigned int i; } c; c.f = f;
    unsigned int x = c.i;
    return (unsigned short)((x + 0x7fffu + ((x >> 16) & 1u)) >> 16);  // RNE
}
static __device__ __forceinline__ unsigned int cvt_pk_bf16(float lo, float hi) {
    unsigned int r;
    asm("v_cvt_pk_bf16_f32 %0, %1, %2" : "=v"(r) : "v"(lo), "v"(hi));
    return r;
}
static __device__ __forceinline__ void gload_lds16(const void* g, void* l) {
    __builtin_amdgcn_global_load_lds((const __attribute__((address_space(1))) void*)g,
                                     (__attribute__((address_space(3))) void*)l, 16, 0, 0);
}

#define BAR() __builtin_amdgcn_s_barrier()
#define WAITL0() asm volatile("s_waitcnt lgkmcnt(0)" ::: "memory")
#define WVM(n) asm volatile("s_waitcnt vmcnt(" #n ")" ::: "memory")
#define MFMA(a, b, c) __builtin_amdgcn_mfma_f32_16x16x32_bf16((a), (b), (c), 0, 0, 0)

// ---------------------------------------------------------------- prep: cast x to bf16
__global__ __launch_bounds__(256) void cast_x_kernel(const float* __restrict__ x,
                                                     unsigned short* __restrict__ xb, int n8) {
    int stride = gridDim.x * blockDim.x;
    for (int i = blockIdx.x * blockDim.x + threadIdx.x; i < n8; i += stride) {
        const float4_t* p = (const float4_t*)(x + (size_t)i * 8);
        float4_t a = p[0], b = p[1];
        ushort8 v;
        v[0] = f2bf(a[0]); v[1] = f2bf(a[1]); v[2] = f2bf(a[2]); v[3] = f2bf(a[3]);
        v[4] = f2bf(b[0]); v[5] = f2bf(b[1]); v[6] = f2bf(b[2]); v[7] = f2bf(b[3]);
        *(ushort8*)(xb + (size_t)i * 8) = v;
    }
}

// ---------------------------------------------------------------- prep: weights + bias
// Wqkv: [1536,512] bf16 row-major.  Wpack: Wo in MFMA-fragment order:
// Wpack[((kt*32 + nf)*64 + lane)*8 + e] = Wo[nf*16 + (lane&15)][kt*32 + (lane>>4)*8 + e]
__global__ __launch_bounds__(256) void prep_w_kernel(
    const float* __restrict__ wq, const float* __restrict__ wk, const float* __restrict__ wv,
    const float* __restrict__ wo,
    const float* __restrict__ bq, const float* __restrict__ bk, const float* __restrict__ bv,
    unsigned short* __restrict__ wqkv, unsigned short* __restrict__ wpack,
    float* __restrict__ bias_qkv) {
    const int WN = DMODEL * DMODEL;  // 262144
    int tid = blockIdx.x * blockDim.x + threadIdx.x;
    int stride = gridDim.x * blockDim.x;
    for (int j = tid; j < 3 * WN; j += stride) {
        int seg = j / WN, idx = j - seg * WN;
        const float* src = (seg == 0) ? wq : (seg == 1) ? wk : wv;
        wqkv[j] = f2bf(src[idx]);
    }
    for (int j = tid; j < WN; j += stride) {
        int e = j & 7, l = (j >> 3) & 63, nf = (j >> 9) & 31, kt = j >> 14;
        int row = nf * 16 + (l & 15);
        int k = kt * 32 + ((l >> 4) << 3) + e;
        wpack[j] = f2bf(wo[row * 512 + k]);
    }
    for (int j = tid; j < QKVN; j += stride)
        bias_qkv[j] = (j < 512) ? bq[j] : (j < 1024) ? bk[j - 512] : bv[j - 1024];
}

// ---------------------------------------------------------------- GEMM1: QKV = Xb @ Wqkv^T + bias
// 256x256 tile, BK=32, 8 waves (2x4), 4-slot circular LDS pipeline (128 KB),
// counted vmcnt (never 0 in steady state), XOR-swizzled LDS, XCD block swizzle.
__global__ __launch_bounds__(512, 2) void gemm1_kernel(
    const unsigned short* __restrict__ A, const unsigned short* __restrict__ Bw,
    const float* __restrict__ bias, unsigned short* __restrict__ Cout) {
    __shared__ unsigned short As[4][256 * 32];  // 64 KB
    __shared__ unsigned short Bs[4][256 * 32];  // 64 KB

    const int b = blockIdx.x;                   // grid = 1536 = 8 * 192
    const int L = (b & 7) * 192 + (b >> 3);     // bijective XCD swizzle
    const int bm = L / 6;
    const int bn = L - bm * 6;

    const int t = threadIdx.x;
    const int lane = t & 63;
    const int w = t >> 6;
    const int wm = w >> 2, wn = w & 3;          // 2 x 4 waves

    const unsigned short* Ab = A + (size_t)bm * 256 * 512;
    const unsigned short* Bb = Bw + (size_t)bn * 256 * 512;

    // staging addressing: LDS linear dest, global source inverse-swizzled
    const int i0 = t, i1 = 512 + t;
    const int r0 = i0 >> 2, s0 = (i0 & 3) ^ ((r0 >> 1) & 3);
    const int r1 = i1 >> 2, s1 = (i1 & 3) ^ ((r1 >> 1) & 3);

#define STAGE_A1(kt) do { \
        gload_lds16(Ab + r0 * 512 + (kt) * 32 + s0 * 8, &As[(kt) & 3][i0 * 8]); \
        gload_lds16(Ab + r1 * 512 + (kt) * 32 + s1 * 8, &As[(kt) & 3][i1 * 8]); } while (0)
#define STAGE_B1(kt) do { \
        gload_lds16(Bb + r0 * 512 + (kt) * 32 + s0 * 8, &Bs[(kt) & 3][i0 * 8]); \
        gload_lds16(Bb + r1 * 512 + (kt) * 32 + s1 * 8, &Bs[(kt) & 3][i1 * 8]); } while (0)

    // fragment read offsets (swizzled): p = (lane>>4) ^ ((row>>1)&3)
    int aoff[8], boff[4];
#pragma unroll
    for (int m = 0; m < 8; m++) {
        int row = wm * 128 + m * 16 + (lane & 15);
        aoff[m] = row * 32 + (((lane >> 4) ^ ((row >> 1) & 3)) * 8);
    }
#pragma unroll
    for (int n = 0; n < 4; n++) {
        int row = wn * 64 + n * 16 + (lane & 15);
        boff[n] = row * 32 + (((lane >> 4) ^ ((row >> 1) & 3)) * 8);
    }

    float4_t acc[8][4];
#pragma unroll
    for (int m = 0; m < 8; m++)
#pragma unroll
        for (int n = 0; n < 4; n++) acc[m][n] = (float4_t){0.f, 0.f, 0.f, 0.f};

    // prologue: stage K-tiles 0,1,2 (12 loads); wait tile 0 (8 remain in flight)
    STAGE_A1(0); STAGE_B1(0);
    STAGE_A1(1); STAGE_B1(1);
    STAGE_A1(2); STAGE_B1(2);
    WVM(8);
    BAR();

    short8 ar[8], br[4];
#pragma unroll
    for (int kt = 0; kt < 16; ++kt) {
        const int sl = kt & 3;
        // ---- phase 0: read A frags + B n0/n1, stage A of kt+3, MFMA n-half 0
#pragma unroll
        for (int m = 0; m < 8; m++) ar[m] = *(const short8*)&As[sl][aoff[m]];
        br[0] = *(const short8*)&Bs[sl][boff[0]];
        br[1] = *(const short8*)&Bs[sl][boff[1]];
        if (kt <= 12) STAGE_A1(kt + 3);
        BAR();
        WAITL0();
        __builtin_amdgcn_s_setprio(1);
#pragma unroll
        for (int m = 0; m < 8; m++) {
            acc[m][0] = MFMA(ar[m], br[0], acc[m][0]);
            acc[m][1] = MFMA(ar[m], br[1], acc[m][1]);
        }
        __builtin_amdgcn_s_setprio(0);
        BAR();
        // ---- phase 1: read B n2/n3, stage B of kt+3, MFMA n-half 1
        br[2] = *(const short8*)&Bs[sl][boff[2]];
        br[3] = *(const short8*)&Bs[sl][boff[3]];
        if (kt <= 12) STAGE_B1(kt + 3);
        BAR();
        WAITL0();
        __builtin_amdgcn_s_setprio(1);
#pragma unroll
        for (int m = 0; m < 8; m++) {
            acc[m][2] = MFMA(ar[m], br[2], acc[m][2]);
            acc[m][3] = MFMA(ar[m], br[3], acc[m][3]);
        }
        __builtin_amdgcn_s_setprio(0);
        // K-tile boundary: ensure tile kt+1 landed; keep 2 tiles (8 loads) in flight
        if (kt <= 12) { WVM(8); }
        else if (kt == 13) { WVM(4); }
        else if (kt == 14) { WVM(0); }
        BAR();
    }

    // ---- epilogue: C/D mapping col=lane&15, row=(lane>>4)*4+j
    const int orow0 = bm * 256 + wm * 128;
    const int ocol0 = bn * 256 + wn * 64;
#pragma unroll
    for (int m = 0; m < 8; m++) {
#pragma unroll
        for (int n = 0; n < 4; n++) {
            int col = ocol0 + n * 16 + (lane & 15);
            float bv = bias[col];
#pragma unroll
            for (int j = 0; j < 4; j++) {
                int row = orow0 + m * 16 + (lane >> 4) * 4 + j;
                Cout[(size_t)row * QKVN + col] = f2bf(acc[m][n][j] + bv);
            }
        }
    }
#undef STAGE_A1
#undef STAGE_B1
}

// ---------------------------------------------------------------- FUSED: attention + O-proj + residual + LN
// Block = 32 tokens, 256 threads = 4 waves.  Code-size-trimmed version:
// phase-1 round loop and phase-2 K-loop NOT unrolled (I$-resident bodies);
// AO tile in XOR-swizzled LDS (32 KB); LN reduce buffer overlaid on AOs.
__global__ __launch_bounds__(256, 4) void attn_o_ln_kernel(
    const unsigned short* __restrict__ qkv, const unsigned short* __restrict__ Wpack,
    const float* __restrict__ bo, const float* __restrict__ xres,
    const float* __restrict__ lng, const float* __restrict__ lnb,
    float* __restrict__ Y) {
    __shared__ __align__(16) unsigned char AOs[32 * 1024];  // 32 rows x 512 bf16, swizzled
    float* red = (float*)AOs;                               // overlaid after phase 2

    const int blk = blockIdx.x;
    const int T0 = blk * 32;
    const int t = threadIdx.x;
    const int lane = t & 63;
    const int w = t >> 6;        // wave id 0..3
    const int g = lane >> 4;     // token subgroup 0..3
    const int sl = lane & 15;    // dim-slice owner: dims [8*sl, 8*sl+8)

    const float scale = 0.08838834764831845f;  // 1/sqrt(128)

    // ---------------- phase 1: attention for this wave's 8 tokens (2 rounds x 4)
#pragma unroll 1
    for (int r = 0; r < 2; ++r) {
        const int tr = w * 8 + r * 4 + g;  // LDS row / relative token
        const unsigned short* base = qkv + (size_t)(T0 + tr) * QKVN + sl * 8;

        short8 qr[4], kr[4], vr[4];
#pragma unroll
        for (int h = 0; h < 4; h++) {
            qr[h] = *(const short8*)(base + h * 128);
            kr[h] = *(const short8*)(base + 512 + h * 128);
            vr[h] = *(const short8*)(base + 1024 + h * 128);
        }
        float qf[4][8];
#pragma unroll
        for (int h = 0; h < 4; h++)
#pragma unroll
            for (int d = 0; d < 8; d++) qf[h][d] = bf2f((unsigned short)qr[h][d]);

        float s[4][4];
#pragma unroll
        for (int h = 0; h < 4; h++)
#pragma unroll
            for (int tt = 0; tt < 4; tt++) s[h][tt] = 0.f;
#pragma unroll
        for (int tt = 0; tt < 4; tt++) {
            float kf[8];
#pragma unroll
            for (int d = 0; d < 8; d++) kf[d] = bf2f((unsigned short)kr[tt][d]);
#pragma unroll
            for (int h = 0; h < 4; h++)
#pragma unroll
                for (int d = 0; d < 8; d++) s[h][tt] += qf[h][d] * kf[d];
        }
        // reduce partial dots across the 16-lane group
#pragma unroll
        for (int mask = 1; mask < 16; mask <<= 1) {
#pragma unroll
            for (int h = 0; h < 4; h++)
#pragma unroll
                for (int tt = 0; tt < 4; tt++)
                    s[h][tt] += __shfl_xor(s[h][tt], mask, 64);
        }
        // softmax (redundant across the 16 lanes, fine)
        float p[4][4];
#pragma unroll
        for (int h = 0; h < 4; h++) {
            float m0 = fmaxf(fmaxf(s[h][0], s[h][1]), fmaxf(s[h][2], s[h][3])) * scale;
            float sum = 0.f;
#pragma unroll
            for (int tt = 0; tt < 4; tt++) { p[h][tt] = __expf(s[h][tt] * scale - m0); sum += p[h][tt]; }
            float rr = __frcp_rn(sum);
#pragma unroll
            for (int tt = 0; tt < 4; tt++) p[h][tt] *= rr;
        }
        // PV: o[h][d] = sum_t p[h][t] * V[t][d] over this lane's 8 dims
        float o[4][8];
#pragma unroll
        for (int h = 0; h < 4; h++)
#pragma unroll
            for (int d = 0; d < 8; d++) o[h][d] = 0.f;
#pragma unroll
        for (int tt = 0; tt < 4; tt++) {
            float vf[8];
#pragma unroll
            for (int d = 0; d < 8; d++) vf[d] = bf2f((unsigned short)vr[tt][d]);
#pragma unroll
            for (int h = 0; h < 4; h++) {
                float ph = p[h][tt];
#pragma unroll
                for (int d = 0; d < 8; d++) o[h][d] += ph * vf[d];
            }
        }
        // pack via v_cvt_pk_bf16_f32 + swizzled LDS write (16B per head)
#pragma unroll
        for (int h = 0; h < 4; h++) {
            uint4_t pk;
            pk[0] = cvt_pk_bf16(o[h][0], o[h][1]);
            pk[1] = cvt_pk_bf16(o[h][2], o[h][3]);
            pk[2] = cvt_pk_bf16(o[h][4], o[h][5]);
            pk[3] = cvt_pk_bf16(o[h][6], o[h][7]);
            int off = tr * 1024 + ((h * 256 + sl * 16) ^ ((tr & 7) << 4));
            *(uint4_t*)(AOs + off) = pk;
        }
    }
    __syncthreads();

    // ---------------- phase 2: [32x512] = AOs @ Wo^T; B streamed from L2, TLP-hidden
    const unsigned short* Bb2 = Wpack + ((size_t)(w * 8) * 64 + lane) * 8;
    const int arow0 = sl;
    const int arow1 = 16 + sl;

    float4_t acc[2][8];
#pragma unroll
    for (int m = 0; m < 2; m++)
#pragma unroll
        for (int n = 0; n < 8; n++) acc[m][n] = (float4_t){0.f, 0.f, 0.f, 0.f};

#pragma unroll 1
    for (int kt = 0; kt < 16; ++kt) {
        short8 bfr[8];
#pragma unroll
        for (int n = 0; n < 8; n++)
            bfr[n] = *(const short8*)(Bb2 + (size_t)kt * 16384 + n * 512);
        int lslot = kt * 64 + (lane >> 4) * 16;
        short8 a0 = *(const short8*)(AOs + arow0 * 1024 + (lslot ^ ((arow0 & 7) << 4)));
        short8 a1 = *(const short8*)(AOs + arow1 * 1024 + (lslot ^ ((arow1 & 7) << 4)));
#pragma unroll
        for (int n = 0; n < 8; n++) {
            acc[0][n] = MFMA(a0, bfr[n], acc[0][n]);
            acc[1][n] = MFMA(a1, bfr[n], acc[1][n]);
        }
    }
    __syncthreads();  // all AOs reads done -> safe to overlay red

    // ---------------- epilogue: bias + residual, LN over the 512-col row, fp32 out
    float bias8[8], gc8[8], bc8[8];
#pragma unroll
    for (int n = 0; n < 8; n++) {
        int c = w * 128 + n * 16 + (lane & 15);
        bias8[n] = bo[c]; gc8[n] = lng[c]; bc8[n] = lnb[c];
    }
#pragma unroll
    for (int m = 0; m < 2; m++) {
#pragma unroll
        for (int j = 0; j < 4; j++) {
            int grow = T0 + m * 16 + (lane >> 4) * 4 + j;
            const float* xr = xres + (size_t)grow * 512;
#pragma unroll
            for (int n = 0; n < 8; n++) {
                int c = w * 128 + n * 16 + (lane & 15);
                acc[m][n][j] += bias8[n] + xr[c];
            }
        }
    }
#pragma unroll
    for (int m = 0; m < 2; m++) {
#pragma unroll
        for (int j = 0; j < 4; j++) {
            float s = 0.f, s2 = 0.f;
#pragma unroll
            for (int n = 0; n < 8; n++) { float v = acc[m][n][j]; s += v; s2 += v * v; }
#pragma unroll
            for (int mask = 1; mask < 16; mask <<= 1) {
                s += __shfl_xor(s, mask, 64);
                s2 += __shfl_xor(s2, mask, 64);
            }
            if ((lane & 15) == 0) {
                int rl = m * 16 + (lane >> 4) * 4 + j;
                red[(w * 32 + rl) * 2 + 0] = s;
                red[(w * 32 + rl) * 2 + 1] = s2;
            }
        }
    }
    __syncthreads();
#pragma unroll
    for (int m = 0; m < 2; m++) {
#pragma unroll
        for (int j = 0; j < 4; j++) {
            int rl = m * 16 + (lane >> 4) * 4 + j;
            float s = 0.f, s2 = 0.f;
#pragma unroll
            for (int i = 0; i < 4; i++) {
                s += red[(i * 32 + rl) * 2 + 0];
                s2 += red[(i * 32 + rl) * 2 + 1];
            }
            float mu = s * (1.f / 512.f);
            float var = s2 * (1.f / 512.f) - mu * mu;
            float inv = rsqrtf(var + LN_EPS);
            int grow = T0 + rl;
            float* yp = Y + (size_t)grow * 512;
#pragma unroll
            for (int n = 0; n < 8; n++) {
                int c = w * 128 + n * 16 + (lane & 15);
                yp[c] = (acc[m][n][j] - mu) * inv * gc8[n] + bc8[n];
            }
        }
    }
}

// ---------------------------------------------------------------- launch
extern "C" void kernel_launch(void* const* d_in, const int* in_sizes, int n_in,
                              void* d_out, int out_size, void* d_ws, size_t ws_size,
                              hipStream_t stream) {
    const float* x   = (const float*)d_in[0];
    const float* wq  = (const float*)d_in[1];
    const float* bq  = (const float*)d_in[2];
    const float* wk  = (const float*)d_in[3];
    const float* bk  = (const float*)d_in[4];
    const float* wv  = (const float*)d_in[5];
    const float* bv  = (const float*)d_in[6];
    const float* wo  = (const float*)d_in[7];
    const float* bo  = (const float*)d_in[8];
    const float* lng = (const float*)d_in[9];
    const float* lnb = (const float*)d_in[10];

    char* ws = (char*)d_ws;
    unsigned short* Xb    = (unsigned short*)(ws);                 //  67,108,864  x bf16
    unsigned short* Wqkv  = (unsigned short*)(ws + 67108864);      //   1,572,864  [1536,512] bf16
    unsigned short* Wpack = (unsigned short*)(ws + 68681728);      //     524,288  Wo packed bf16
    float*          Bqkv  = (float*)        (ws + 69206016);       //       6,144  [1536] f32
    unsigned short* QKV   = (unsigned short*)(ws + 69212160);      // 201,326,592  [N,1536] bf16
    float* Y = (float*)d_out;

    cast_x_kernel<<<2048, 256, 0, stream>>>(x, Xb, NTOK * 512 / 8);
    prep_w_kernel<<<1024, 256, 0, stream>>>(wq, wk, wv, wo, bq, bk, bv, Wqkv, Wpack, Bqkv);

    // QKV projection: [65536,512] x [1536,512]^T -> bf16 [65536,1536]
    gemm1_kernel<<<(NTOK / 256) * (QKVN / 256), 512, 0, stream>>>(Xb, Wqkv, Bqkv, QKV);

    // fused: per-token attention + O-proj + bias + residual + LayerNorm -> fp32 d_out
    attn_o_ln_kernel<<<NTOK / 32, 256, 0, stream>>>(QKV, Wpack, bo, x, lng, lnb, Y);
}

// Round 7
// 381.342 us; speedup vs baseline: 1.0761x; 1.0761x over previous
//
#include <hip/hip_runtime.h>
#include <stdint.h>

#define NTOK 65536     // B*S = 16*4096
#define DMODEL 512
#define QKVN 1536
#define LN_EPS 1e-5f

typedef __attribute__((ext_vector_type(8))) short short8;
typedef __attribute__((ext_vector_type(8))) unsigned short ushort8;
typedef __attribute__((ext_vector_type(4))) float float4_t;
typedef __attribute__((ext_vector_type(4))) unsigned int uint4_t;

static __device__ __forceinline__ float bf2f(unsigned short u) {
    union { unsigned int i; float f; } c; c.i = ((unsigned int)u) << 16; return c.f;
}
static __device__ __forceinline__ unsigned short f2bf(float f) {
    union { float f; unsigned int i; } c; c.f = f;
    unsigned int x = c.i;
    return (unsigned short)((x + 0x7fffu + ((x >> 16) & 1u)) >> 16);  // RNE
}
static __device__ __forceinline__ unsigned int cvt_pk_bf16(float lo, float hi) {
    unsigned int r;
    asm("v_cvt_pk_bf16_f32 %0, %1, %2" : "=v"(r) : "v"(lo), "v"(hi));
    return r;
}
static __device__ __forceinline__ void gload_lds16(const void* g, void* l) {
    __builtin_amdgcn_global_load_lds((const __attribute__((address_space(1))) void*)g,
                                     (__attribute__((address_space(3))) void*)l, 16, 0, 0);
}

#define BAR() __builtin_amdgcn_s_barrier()
#define WAITL0() asm volatile("s_waitcnt lgkmcnt(0)" ::: "memory")
#define WVM(n) asm volatile("s_waitcnt vmcnt(" #n ")" ::: "memory")
#define MFMA(a, b, c) __builtin_amdgcn_mfma_f32_16x16x32_bf16((a), (b), (c), 0, 0, 0)

// ---------------------------------------------------------------- prep: cast x to bf16
__global__ __launch_bounds__(256) void cast_x_kernel(const float* __restrict__ x,
                                                     unsigned short* __restrict__ xb, int n8) {
    int stride = gridDim.x * blockDim.x;
    for (int i = blockIdx.x * blockDim.x + threadIdx.x; i < n8; i += stride) {
        const float4_t* p = (const float4_t*)(x + (size_t)i * 8);
        float4_t a = p[0], b = p[1];
        ushort8 v;
        v[0] = f2bf(a[0]); v[1] = f2bf(a[1]); v[2] = f2bf(a[2]); v[3] = f2bf(a[3]);
        v[4] = f2bf(b[0]); v[5] = f2bf(b[1]); v[6] = f2bf(b[2]); v[7] = f2bf(b[3]);
        *(ushort8*)(xb + (size_t)i * 8) = v;
    }
}

// ---------------------------------------------------------------- prep: weights + bias
// Wqkv: [1536,512] bf16 row-major.  Wpack: Wo in MFMA-fragment order:
// Wpack[((kt*32 + nf)*64 + lane)*8 + e] = Wo[nf*16 + (lane&15)][kt*32 + (lane>>4)*8 + e]
__global__ __launch_bounds__(256) void prep_w_kernel(
    const float* __restrict__ wq, const float* __restrict__ wk, const float* __restrict__ wv,
    const float* __restrict__ wo,
    const float* __restrict__ bq, const float* __restrict__ bk, const float* __restrict__ bv,
    unsigned short* __restrict__ wqkv, unsigned short* __restrict__ wpack,
    float* __restrict__ bias_qkv) {
    const int WN = DMODEL * DMODEL;  // 262144
    int tid = blockIdx.x * blockDim.x + threadIdx.x;
    int stride = gridDim.x * blockDim.x;
    for (int j = tid; j < 3 * WN; j += stride) {
        int seg = j / WN, idx = j - seg * WN;
        const float* src = (seg == 0) ? wq : (seg == 1) ? wk : wv;
        wqkv[j] = f2bf(src[idx]);
    }
    for (int j = tid; j < WN; j += stride) {
        int e = j & 7, l = (j >> 3) & 63, nf = (j >> 9) & 31, kt = j >> 14;
        int row = nf * 16 + (l & 15);
        int k = kt * 32 + ((l >> 4) << 3) + e;
        wpack[j] = f2bf(wo[row * 512 + k]);
    }
    for (int j = tid; j < QKVN; j += stride)
        bias_qkv[j] = (j < 512) ? bq[j] : (j < 1024) ? bk[j - 512] : bv[j - 1024];
}

// ---------------------------------------------------------------- GEMM1: QKV = Xb @ Wqkv^T + bias
// 256x256 tile, BK=32, 8 waves (2x4), 4-slot circular LDS pipeline (128 KB),
// counted vmcnt (never 0 in steady state), XOR-swizzled LDS, XCD block swizzle.
__global__ __launch_bounds__(512, 2) void gemm1_kernel(
    const unsigned short* __restrict__ A, const unsigned short* __restrict__ Bw,
    const float* __restrict__ bias, unsigned short* __restrict__ Cout) {
    __shared__ unsigned short As[4][256 * 32];  // 64 KB
    __shared__ unsigned short Bs[4][256 * 32];  // 64 KB

    const int b = blockIdx.x;                   // grid = 1536 = 8 * 192
    const int L = (b & 7) * 192 + (b >> 3);     // bijective XCD swizzle
    const int bm = L / 6;
    const int bn = L - bm * 6;

    const int t = threadIdx.x;
    const int lane = t & 63;
    const int w = t >> 6;
    const int wm = w >> 2, wn = w & 3;          // 2 x 4 waves

    const unsigned short* Ab = A + (size_t)bm * 256 * 512;
    const unsigned short* Bb = Bw + (size_t)bn * 256 * 512;

    // staging addressing: LDS linear dest, global source inverse-swizzled
    const int i0 = t, i1 = 512 + t;
    const int r0 = i0 >> 2, s0 = (i0 & 3) ^ ((r0 >> 1) & 3);
    const int r1 = i1 >> 2, s1 = (i1 & 3) ^ ((r1 >> 1) & 3);

#define STAGE_A1(kt) do { \
        gload_lds16(Ab + r0 * 512 + (kt) * 32 + s0 * 8, &As[(kt) & 3][i0 * 8]); \
        gload_lds16(Ab + r1 * 512 + (kt) * 32 + s1 * 8, &As[(kt) & 3][i1 * 8]); } while (0)
#define STAGE_B1(kt) do { \
        gload_lds16(Bb + r0 * 512 + (kt) * 32 + s0 * 8, &Bs[(kt) & 3][i0 * 8]); \
        gload_lds16(Bb + r1 * 512 + (kt) * 32 + s1 * 8, &Bs[(kt) & 3][i1 * 8]); } while (0)

    // fragment read offsets (swizzled): p = (lane>>4) ^ ((row>>1)&3)
    int aoff[8], boff[4];
#pragma unroll
    for (int m = 0; m < 8; m++) {
        int row = wm * 128 + m * 16 + (lane & 15);
        aoff[m] = row * 32 + (((lane >> 4) ^ ((row >> 1) & 3)) * 8);
    }
#pragma unroll
    for (int n = 0; n < 4; n++) {
        int row = wn * 64 + n * 16 + (lane & 15);
        boff[n] = row * 32 + (((lane >> 4) ^ ((row >> 1) & 3)) * 8);
    }

    float4_t acc[8][4];
#pragma unroll
    for (int m = 0; m < 8; m++)
#pragma unroll
        for (int n = 0; n < 4; n++) acc[m][n] = (float4_t){0.f, 0.f, 0.f, 0.f};

    // prologue: stage K-tiles 0,1,2 (12 loads); wait tile 0 (8 remain in flight)
    STAGE_A1(0); STAGE_B1(0);
    STAGE_A1(1); STAGE_B1(1);
    STAGE_A1(2); STAGE_B1(2);
    WVM(8);
    BAR();

    short8 ar[8], br[4];
#pragma unroll
    for (int kt = 0; kt < 16; ++kt) {
        const int sl = kt & 3;
        // ---- phase 0: read A frags + B n0/n1, stage A of kt+3, MFMA n-half 0
#pragma unroll
        for (int m = 0; m < 8; m++) ar[m] = *(const short8*)&As[sl][aoff[m]];
        br[0] = *(const short8*)&Bs[sl][boff[0]];
        br[1] = *(const short8*)&Bs[sl][boff[1]];
        if (kt <= 12) STAGE_A1(kt + 3);
        BAR();
        WAITL0();
        __builtin_amdgcn_s_setprio(1);
#pragma unroll
        for (int m = 0; m < 8; m++) {
            acc[m][0] = MFMA(ar[m], br[0], acc[m][0]);
            acc[m][1] = MFMA(ar[m], br[1], acc[m][1]);
        }
        __builtin_amdgcn_s_setprio(0);
        BAR();
        // ---- phase 1: read B n2/n3, stage B of kt+3, MFMA n-half 1
        br[2] = *(const short8*)&Bs[sl][boff[2]];
        br[3] = *(const short8*)&Bs[sl][boff[3]];
        if (kt <= 12) STAGE_B1(kt + 3);
        BAR();
        WAITL0();
        __builtin_amdgcn_s_setprio(1);
#pragma unroll
        for (int m = 0; m < 8; m++) {
            acc[m][2] = MFMA(ar[m], br[2], acc[m][2]);
            acc[m][3] = MFMA(ar[m], br[3], acc[m][3]);
        }
        __builtin_amdgcn_s_setprio(0);
        // K-tile boundary: ensure tile kt+1 landed; keep 2 tiles (8 loads) in flight
        if (kt <= 12) { WVM(8); }
        else if (kt == 13) { WVM(4); }
        else if (kt == 14) { WVM(0); }
        BAR();
    }

    // ---- epilogue: C/D mapping col=lane&15, row=(lane>>4)*4+j
    const int orow0 = bm * 256 + wm * 128;
    const int ocol0 = bn * 256 + wn * 64;
#pragma unroll
    for (int m = 0; m < 8; m++) {
#pragma unroll
        for (int n = 0; n < 4; n++) {
            int col = ocol0 + n * 16 + (lane & 15);
            float bv = bias[col];
#pragma unroll
            for (int j = 0; j < 4; j++) {
                int row = orow0 + m * 16 + (lane >> 4) * 4 + j;
                Cout[(size_t)row * QKVN + col] = f2bf(acc[m][n][j] + bv);
            }
        }
    }
#undef STAGE_A1
#undef STAGE_B1
}

// ---------------------------------------------------------------- FUSED: attention + O-proj + residual + LN
// Block = 32 tokens, 256 threads = 4 waves, targeting 16 waves/CU (no spill).
// Phase 1: per-HEAD independent in-register attention (low live-register peak),
//          AO tile -> XOR-swizzled LDS (exactly 32 KB).
// Phase 2: MFMA, A from LDS, B streamed from L2 (unroll 1).
// Epilogue: bias + resid + full-row LN; red buffer overlaid on AOs (transposed
//           layout -> broadcast reads, no bank conflicts).
__global__ __launch_bounds__(256, 4) void attn_o_ln_kernel(
    const unsigned short* __restrict__ qkv, const unsigned short* __restrict__ Wpack,
    const float* __restrict__ bo, const float* __restrict__ xres,
    const float* __restrict__ lng, const float* __restrict__ lnb,
    float* __restrict__ Y) {
    __shared__ __align__(16) unsigned char AOs[32 * 1024];  // 32 rows x 512 bf16, swizzled
    float* red = (float*)AOs;                               // overlaid after phase 2

    const int T0 = blockIdx.x * 32;
    const int t = threadIdx.x;
    const int lane = t & 63;
    const int w = t >> 6;        // wave id 0..3
    const int g = lane >> 4;     // token subgroup 0..3
    const int sl = lane & 15;    // dim-slice owner: dims [8*sl, 8*sl+8)

    const float scale = 0.08838834764831845f;  // 1/sqrt(128)

    // ---------------- phase 1: attention, per-head independent (2 rounds x 4 tokens/wave)
#pragma unroll 1
    for (int r = 0; r < 2; ++r) {
        const int tr = w * 8 + r * 4 + g;  // LDS row / relative token
        const unsigned short* base = qkv + (size_t)(T0 + tr) * QKVN + sl * 8;

        short8 qr[4], kr[4], vr[4];
#pragma unroll
        for (int h = 0; h < 4; h++) {
            qr[h] = *(const short8*)(base + h * 128);
            kr[h] = *(const short8*)(base + 512 + h * 128);
            vr[h] = *(const short8*)(base + 1024 + h * 128);
        }
#pragma unroll
        for (int h = 0; h < 4; h++) {
            float qf[8];
#pragma unroll
            for (int d = 0; d < 8; d++) qf[d] = bf2f((unsigned short)qr[h][d]);
            float s[4];
#pragma unroll
            for (int tt = 0; tt < 4; tt++) {
                float a0 = 0.f;
#pragma unroll
                for (int d = 0; d < 8; d++) a0 += qf[d] * bf2f((unsigned short)kr[tt][d]);
                s[tt] = a0;
            }
            // reduce partial dots across the 16-lane group
#pragma unroll
            for (int mask = 1; mask < 16; mask <<= 1)
#pragma unroll
                for (int tt = 0; tt < 4; tt++)
                    s[tt] += __shfl_xor(s[tt], mask, 64);
            // softmax (redundant across 16 lanes)
            float m0 = fmaxf(fmaxf(s[0], s[1]), fmaxf(s[2], s[3])) * scale;
            float p[4];
            float sum = 0.f;
#pragma unroll
            for (int tt = 0; tt < 4; tt++) { p[tt] = __expf(s[tt] * scale - m0); sum += p[tt]; }
            float rr = __frcp_rn(sum);
            // PV over this lane's 8 dims
            float o[8];
#pragma unroll
            for (int d = 0; d < 8; d++) o[d] = 0.f;
#pragma unroll
            for (int tt = 0; tt < 4; tt++) {
                float ph = p[tt] * rr;
#pragma unroll
                for (int d = 0; d < 8; d++) o[d] += ph * bf2f((unsigned short)vr[tt][d]);
            }
            // pack + swizzled LDS write (16B)
            uint4_t pk;
            pk[0] = cvt_pk_bf16(o[0], o[1]);
            pk[1] = cvt_pk_bf16(o[2], o[3]);
            pk[2] = cvt_pk_bf16(o[4], o[5]);
            pk[3] = cvt_pk_bf16(o[6], o[7]);
            int off = tr * 1024 + ((h * 256 + sl * 16) ^ ((tr & 7) << 4));
            *(uint4_t*)(AOs + off) = pk;
        }
    }
    __syncthreads();

    // ---------------- phase 2: [32x512] = AOs @ Wo^T; B streamed from L2, TLP-hidden
    const unsigned short* Bb2 = Wpack + ((size_t)(w * 8) * 64 + lane) * 8;
    const int arow0 = sl;
    const int arow1 = 16 + sl;

    float4_t acc[2][8];
#pragma unroll
    for (int m = 0; m < 2; m++)
#pragma unroll
        for (int n = 0; n < 8; n++) acc[m][n] = (float4_t){0.f, 0.f, 0.f, 0.f};

#pragma unroll 1
    for (int kt = 0; kt < 16; ++kt) {
        short8 bfr[8];
#pragma unroll
        for (int n = 0; n < 8; n++)
            bfr[n] = *(const short8*)(Bb2 + (size_t)kt * 16384 + n * 512);
        int lslot = kt * 64 + g * 16;
        short8 a0 = *(const short8*)(AOs + arow0 * 1024 + (lslot ^ ((arow0 & 7) << 4)));
        short8 a1 = *(const short8*)(AOs + arow1 * 1024 + (lslot ^ ((arow1 & 7) << 4)));
#pragma unroll
        for (int n = 0; n < 8; n++) {
            acc[0][n] = MFMA(a0, bfr[n], acc[0][n]);
            acc[1][n] = MFMA(a1, bfr[n], acc[1][n]);
        }
    }
    __syncthreads();  // all AOs reads done -> safe to overlay red

    // ---------------- epilogue: bias + residual, LN over the 512-col row, fp32 out
    float bias8[8], gc8[8], bc8[8];
#pragma unroll
    for (int n = 0; n < 8; n++) {
        int c = w * 128 + n * 16 + sl;
        bias8[n] = bo[c]; gc8[n] = lng[c]; bc8[n] = lnb[c];
    }
#pragma unroll
    for (int m = 0; m < 2; m++) {
#pragma unroll
        for (int j = 0; j < 4; j++) {
            int grow = T0 + m * 16 + g * 4 + j;
            const float* xr = xres + (size_t)grow * 512;
#pragma unroll
            for (int n = 0; n < 8; n++)
                acc[m][n][j] += bias8[n] + xr[w * 128 + n * 16 + sl];
        }
    }
    // per-row partials over this wave's 128 cols; 16-lane butterfly; red[rl][wave]
#pragma unroll
    for (int m = 0; m < 2; m++) {
#pragma unroll
        for (int j = 0; j < 4; j++) {
            float s = 0.f, s2 = 0.f;
#pragma unroll
            for (int n = 0; n < 8; n++) { float v = acc[m][n][j]; s += v; s2 += v * v; }
#pragma unroll
            for (int mask = 1; mask < 16; mask <<= 1) {
                s += __shfl_xor(s, mask, 64);
                s2 += __shfl_xor(s2, mask, 64);
            }
            if (sl == 0) {
                int rl = m * 16 + g * 4 + j;
                red[(rl * 4 + w) * 2 + 0] = s;
                red[(rl * 4 + w) * 2 + 1] = s2;
            }
        }
    }
    __syncthreads();
#pragma unroll
    for (int m = 0; m < 2; m++) {
#pragma unroll
        for (int j = 0; j < 4; j++) {
            int rl = m * 16 + g * 4 + j;
            float s = 0.f, s2 = 0.f;
#pragma unroll
            for (int i = 0; i < 4; i++) {
                s += red[(rl * 4 + i) * 2 + 0];
                s2 += red[(rl * 4 + i) * 2 + 1];
            }
            float mu = s * (1.f / 512.f);
            float var = s2 * (1.f / 512.f) - mu * mu;
            float inv = rsqrtf(var + LN_EPS);
            float* yp = Y + (size_t)(T0 + rl) * 512;
#pragma unroll
            for (int n = 0; n < 8; n++) {
                int c = w * 128 + n * 16 + sl;
                yp[c] = (acc[m][n][j] - mu) * inv * gc8[n] + bc8[n];
            }
        }
    }
}

// ---------------------------------------------------------------- launch
extern "C" void kernel_launch(void* const* d_in, const int* in_sizes, int n_in,
                              void* d_out, int out_size, void* d_ws, size_t ws_size,
                              hipStream_t stream) {
    const float* x   = (const float*)d_in[0];
    const float* wq  = (const float*)d_in[1];
    const float* bq  = (const float*)d_in[2];
    const float* wk  = (const float*)d_in[3];
    const float* bk  = (const float*)d_in[4];
    const float* wv  = (const float*)d_in[5];
    const float* bv  = (const float*)d_in[6];
    const float* wo  = (const float*)d_in[7];
    const float* bo  = (const float*)d_in[8];
    const float* lng = (const float*)d_in[9];
    const float* lnb = (const float*)d_in[10];

    char* ws = (char*)d_ws;
    unsigned short* Xb    = (unsigned short*)(ws);                 //  67,108,864  x bf16
    unsigned short* Wqkv  = (unsigned short*)(ws + 67108864);      //   1,572,864  [1536,512] bf16
    unsigned short* Wpack = (unsigned short*)(ws + 68681728);      //     524,288  Wo packed bf16
    float*          Bqkv  = (float*)        (ws + 69206016);       //       6,144  [1536] f32
    unsigned short* QKV   = (unsigned short*)(ws + 69212160);      // 201,326,592  [N,1536] bf16
    float* Y = (float*)d_out;

    cast_x_kernel<<<2048, 256, 0, stream>>>(x, Xb, NTOK * 512 / 8);
    prep_w_kernel<<<1024, 256, 0, stream>>>(wq, wk, wv, wo, bq, bk, bv, Wqkv, Wpack, Bqkv);

    // QKV projection: [65536,512] x [1536,512]^T -> bf16 [65536,1536]
    gemm1_kernel<<<(NTOK / 256) * (QKVN / 256), 512, 0, stream>>>(Xb, Wqkv, Bqkv, QKV);

    // fused: per-token attention + O-proj + bias + residual + LayerNorm -> fp32 d_out
    attn_o_ln_kernel<<<NTOK / 32, 256, 0, stream>>>(QKV, Wpack, bo, x, lng, lnb, Y);
}

// Round 8
// 332.956 us; speedup vs baseline: 1.2325x; 1.1453x over previous
//
#include <hip/hip_runtime.h>
#include <stdint.h>

#define NTOK 65536     // B*S = 16*4096
#define DMODEL 512
#define QKVN 1536
#define LN_EPS 1e-5f

typedef __attribute__((ext_vector_type(8))) short short8;
typedef __attribute__((ext_vector_type(8))) unsigned short ushort8;
typedef __attribute__((ext_vector_type(4))) float float4_t;
typedef __attribute__((ext_vector_type(4))) unsigned int uint4_t;

static __device__ __forceinline__ float bf2f(unsigned short u) {
    union { unsigned int i; float f; } c; c.i = ((unsigned int)u) << 16; return c.f;
}
static __device__ __forceinline__ unsigned short f2bf(float f) {
    union { float f; unsigned int i; } c; c.f = f;
    unsigned int x = c.i;
    return (unsigned short)((x + 0x7fffu + ((x >> 16) & 1u)) >> 16);  // RNE
}
static __device__ __forceinline__ unsigned int cvt_pk_bf16(float lo, float hi) {
    unsigned int r;
    asm("v_cvt_pk_bf16_f32 %0, %1, %2" : "=v"(r) : "v"(lo), "v"(hi));
    return r;
}
static __device__ __forceinline__ void gload_lds16(const void* g, void* l) {
    __builtin_amdgcn_global_load_lds((const __attribute__((address_space(1))) void*)g,
                                     (__attribute__((address_space(3))) void*)l, 16, 0, 0);
}

#define BAR() __builtin_amdgcn_s_barrier()
#define WAITL0() asm volatile("s_waitcnt lgkmcnt(0)" ::: "memory")
#define WVM(n) asm volatile("s_waitcnt vmcnt(" #n ")" ::: "memory")
#define MFMA(a, b, c) __builtin_amdgcn_mfma_f32_16x16x32_bf16((a), (b), (c), 0, 0, 0)

// ---------------------------------------------------------------- prep: cast x to bf16
__global__ __launch_bounds__(256) void cast_x_kernel(const float* __restrict__ x,
                                                     unsigned short* __restrict__ xb, int n8) {
    int stride = gridDim.x * blockDim.x;
    for (int i = blockIdx.x * blockDim.x + threadIdx.x; i < n8; i += stride) {
        const float4_t* p = (const float4_t*)(x + (size_t)i * 8);
        float4_t a = p[0], b = p[1];
        ushort8 v;
        v[0] = f2bf(a[0]); v[1] = f2bf(a[1]); v[2] = f2bf(a[2]); v[3] = f2bf(a[3]);
        v[4] = f2bf(b[0]); v[5] = f2bf(b[1]); v[6] = f2bf(b[2]); v[7] = f2bf(b[3]);
        *(ushort8*)(xb + (size_t)i * 8) = v;
    }
}

// ---------------------------------------------------------------- prep: weights + bias
// Wqkv: [1536,512] bf16 row-major.  Wpack: Wo in MFMA-fragment order:
// Wpack[((kt*32 + nf)*64 + lane)*8 + e] = Wo[nf*16 + (lane&15)][kt*32 + (lane>>4)*8 + e]
__global__ __launch_bounds__(256) void prep_w_kernel(
    const float* __restrict__ wq, const float* __restrict__ wk, const float* __restrict__ wv,
    const float* __restrict__ wo,
    const float* __restrict__ bq, const float* __restrict__ bk, const float* __restrict__ bv,
    unsigned short* __restrict__ wqkv, unsigned short* __restrict__ wpack,
    float* __restrict__ bias_qkv) {
    const int WN = DMODEL * DMODEL;  // 262144
    int tid = blockIdx.x * blockDim.x + threadIdx.x;
    int stride = gridDim.x * blockDim.x;
    for (int j = tid; j < 3 * WN; j += stride) {
        int seg = j / WN, idx = j - seg * WN;
        const float* src = (seg == 0) ? wq : (seg == 1) ? wk : wv;
        wqkv[j] = f2bf(src[idx]);
    }
    for (int j = tid; j < WN; j += stride) {
        int e = j & 7, l = (j >> 3) & 63, nf = (j >> 9) & 31, kt = j >> 14;
        int row = nf * 16 + (l & 15);
        int k = kt * 32 + ((l >> 4) << 3) + e;
        wpack[j] = f2bf(wo[row * 512 + k]);
    }
    for (int j = tid; j < QKVN; j += stride)
        bias_qkv[j] = (j < 512) ? bq[j] : (j < 1024) ? bk[j - 512] : bv[j - 1024];
}

// ---------------------------------------------------------------- GEMM1: QKV = Xb @ Wqkv^T + bias
// 256x256 tile, BK=32, 8 waves (2x4), 4-slot circular LDS pipeline (128 KB),
// counted vmcnt (never 0 in steady state), XOR-swizzled LDS, XCD block swizzle.
__global__ __launch_bounds__(512, 2) void gemm1_kernel(
    const unsigned short* __restrict__ A, const unsigned short* __restrict__ Bw,
    const float* __restrict__ bias, unsigned short* __restrict__ Cout) {
    __shared__ unsigned short As[4][256 * 32];  // 64 KB
    __shared__ unsigned short Bs[4][256 * 32];  // 64 KB

    const int b = blockIdx.x;                   // grid = 1536 = 8 * 192
    const int L = (b & 7) * 192 + (b >> 3);     // bijective XCD swizzle
    const int bm = L / 6;
    const int bn = L - bm * 6;

    const int t = threadIdx.x;
    const int lane = t & 63;
    const int w = t >> 6;
    const int wm = w >> 2, wn = w & 3;          // 2 x 4 waves

    const unsigned short* Ab = A + (size_t)bm * 256 * 512;
    const unsigned short* Bb = Bw + (size_t)bn * 256 * 512;

    // staging addressing: LDS linear dest, global source inverse-swizzled
    const int i0 = t, i1 = 512 + t;
    const int r0 = i0 >> 2, s0 = (i0 & 3) ^ ((r0 >> 1) & 3);
    const int r1 = i1 >> 2, s1 = (i1 & 3) ^ ((r1 >> 1) & 3);

#define STAGE_A1(kt) do { \
        gload_lds16(Ab + r0 * 512 + (kt) * 32 + s0 * 8, &As[(kt) & 3][i0 * 8]); \
        gload_lds16(Ab + r1 * 512 + (kt) * 32 + s1 * 8, &As[(kt) & 3][i1 * 8]); } while (0)
#define STAGE_B1(kt) do { \
        gload_lds16(Bb + r0 * 512 + (kt) * 32 + s0 * 8, &Bs[(kt) & 3][i0 * 8]); \
        gload_lds16(Bb + r1 * 512 + (kt) * 32 + s1 * 8, &Bs[(kt) & 3][i1 * 8]); } while (0)

    // fragment read offsets (swizzled): p = (lane>>4) ^ ((row>>1)&3)
    int aoff[8], boff[4];
#pragma unroll
    for (int m = 0; m < 8; m++) {
        int row = wm * 128 + m * 16 + (lane & 15);
        aoff[m] = row * 32 + (((lane >> 4) ^ ((row >> 1) & 3)) * 8);
    }
#pragma unroll
    for (int n = 0; n < 4; n++) {
        int row = wn * 64 + n * 16 + (lane & 15);
        boff[n] = row * 32 + (((lane >> 4) ^ ((row >> 1) & 3)) * 8);
    }

    float4_t acc[8][4];
#pragma unroll
    for (int m = 0; m < 8; m++)
#pragma unroll
        for (int n = 0; n < 4; n++) acc[m][n] = (float4_t){0.f, 0.f, 0.f, 0.f};

    // prologue: stage K-tiles 0,1,2 (12 loads); wait tile 0 (8 remain in flight)
    STAGE_A1(0); STAGE_B1(0);
    STAGE_A1(1); STAGE_B1(1);
    STAGE_A1(2); STAGE_B1(2);
    WVM(8);
    BAR();

    short8 ar[8], br[4];
#pragma unroll
    for (int kt = 0; kt < 16; ++kt) {
        const int sl = kt & 3;
        // ---- phase 0: read A frags + B n0/n1, stage A of kt+3, MFMA n-half 0
#pragma unroll
        for (int m = 0; m < 8; m++) ar[m] = *(const short8*)&As[sl][aoff[m]];
        br[0] = *(const short8*)&Bs[sl][boff[0]];
        br[1] = *(const short8*)&Bs[sl][boff[1]];
        if (kt <= 12) STAGE_A1(kt + 3);
        BAR();
        WAITL0();
        __builtin_amdgcn_s_setprio(1);
#pragma unroll
        for (int m = 0; m < 8; m++) {
            acc[m][0] = MFMA(ar[m], br[0], acc[m][0]);
            acc[m][1] = MFMA(ar[m], br[1], acc[m][1]);
        }
        __builtin_amdgcn_s_setprio(0);
        BAR();
        // ---- phase 1: read B n2/n3, stage B of kt+3, MFMA n-half 1
        br[2] = *(const short8*)&Bs[sl][boff[2]];
        br[3] = *(const short8*)&Bs[sl][boff[3]];
        if (kt <= 12) STAGE_B1(kt + 3);
        BAR();
        WAITL0();
        __builtin_amdgcn_s_setprio(1);
#pragma unroll
        for (int m = 0; m < 8; m++) {
            acc[m][2] = MFMA(ar[m], br[2], acc[m][2]);
            acc[m][3] = MFMA(ar[m], br[3], acc[m][3]);
        }
        __builtin_amdgcn_s_setprio(0);
        // K-tile boundary: ensure tile kt+1 landed; keep 2 tiles (8 loads) in flight
        if (kt <= 12) { WVM(8); }
        else if (kt == 13) { WVM(4); }
        else if (kt == 14) { WVM(0); }
        BAR();
    }

    // ---- epilogue: C/D mapping col=lane&15, row=(lane>>4)*4+j
    const int orow0 = bm * 256 + wm * 128;
    const int ocol0 = bn * 256 + wn * 64;
#pragma unroll
    for (int m = 0; m < 8; m++) {
#pragma unroll
        for (int n = 0; n < 4; n++) {
            int col = ocol0 + n * 16 + (lane & 15);
            float bv = bias[col];
#pragma unroll
            for (int j = 0; j < 4; j++) {
                int row = orow0 + m * 16 + (lane >> 4) * 4 + j;
                Cout[(size_t)row * QKVN + col] = f2bf(acc[m][n][j] + bv);
            }
        }
    }
#undef STAGE_A1
#undef STAGE_B1
}

// ---------------------------------------------------------------- FUSED: attention + O-proj + residual + LN
// Block = 32 tokens, 512 threads = 8 waves (2m x 4n), 16 waves/CU target.
// Phase 1: single round, per-head in-register attention (4 tokens/wave).
// Phase 2: wave = 1 m-frag x 8 n-frags -> acc 32 regs; A from swizzled LDS,
//          B streamed from L2 (unroll 1).
// Epilogue: bias + resid + full-row LN; red overlaid on AOs.
__global__ __launch_bounds__(512, 4) void attn_o_ln_kernel(
    const unsigned short* __restrict__ qkv, const unsigned short* __restrict__ Wpack,
    const float* __restrict__ bo, const float* __restrict__ xres,
    const float* __restrict__ lng, const float* __restrict__ lnb,
    float* __restrict__ Y) {
    __shared__ __align__(16) unsigned char AOs[32 * 1024];  // 32 rows x 512 bf16, swizzled
    float* red = (float*)AOs;                               // overlaid after phase 2

    const int T0 = blockIdx.x * 32;
    const int t = threadIdx.x;
    const int lane = t & 63;
    const int w = t >> 6;        // wave id 0..7
    const int g = lane >> 4;     // token subgroup 0..3
    const int sl = lane & 15;    // dim-slice owner: dims [8*sl, 8*sl+8)
    const int wm = w >> 2;       // m-half 0..1
    const int wn = w & 3;        // n-quarter 0..3

    const float scale = 0.08838834764831845f;  // 1/sqrt(128)

    // ---------------- phase 1: attention, per-head independent, 1 round (tr = w*4+g)
    {
        const int tr = w * 4 + g;  // LDS row / relative token
        const unsigned short* base = qkv + (size_t)(T0 + tr) * QKVN + sl * 8;

#pragma unroll
        for (int h = 0; h < 4; h++) {
            short8 qr = *(const short8*)(base + h * 128);
            short8 kr[4];
            kr[0] = *(const short8*)(base + 512 + h * 128);
            short8 vr[4];
            vr[0] = *(const short8*)(base + 1024 + h * 128);
            // (only head h's K/V needed; reuse same row for all tt? No --
            // scores are q_h . k_t over HEAD axis: need K of head tt.)
            kr[1] = kr[0]; vr[1] = vr[0];  // placeholders, overwritten below
            // load K,V of all four heads for the dot/PV over the head axis
#pragma unroll
            for (int tt = 0; tt < 4; tt++) {
                kr[tt] = *(const short8*)(base + 512 + tt * 128);
                vr[tt] = *(const short8*)(base + 1024 + tt * 128);
            }
            float qf[8];
#pragma unroll
            for (int d = 0; d < 8; d++) qf[d] = bf2f((unsigned short)qr[d]);
            float s[4];
#pragma unroll
            for (int tt = 0; tt < 4; tt++) {
                float a0 = 0.f;
#pragma unroll
                for (int d = 0; d < 8; d++) a0 += qf[d] * bf2f((unsigned short)kr[tt][d]);
                s[tt] = a0;
            }
#pragma unroll
            for (int mask = 1; mask < 16; mask <<= 1)
#pragma unroll
                for (int tt = 0; tt < 4; tt++)
                    s[tt] += __shfl_xor(s[tt], mask, 64);
            float m0 = fmaxf(fmaxf(s[0], s[1]), fmaxf(s[2], s[3])) * scale;
            float p[4];
            float sum = 0.f;
#pragma unroll
            for (int tt = 0; tt < 4; tt++) { p[tt] = __expf(s[tt] * scale - m0); sum += p[tt]; }
            float rr = __frcp_rn(sum);
            float o[8];
#pragma unroll
            for (int d = 0; d < 8; d++) o[d] = 0.f;
#pragma unroll
            for (int tt = 0; tt < 4; tt++) {
                float ph = p[tt] * rr;
#pragma unroll
                for (int d = 0; d < 8; d++) o[d] += ph * bf2f((unsigned short)vr[tt][d]);
            }
            uint4_t pk;
            pk[0] = cvt_pk_bf16(o[0], o[1]);
            pk[1] = cvt_pk_bf16(o[2], o[3]);
            pk[2] = cvt_pk_bf16(o[4], o[5]);
            pk[3] = cvt_pk_bf16(o[6], o[7]);
            int off = tr * 1024 + ((h * 256 + sl * 16) ^ ((tr & 7) << 4));
            *(uint4_t*)(AOs + off) = pk;
        }
    }
    __syncthreads();

    // ---------------- phase 2: [32x512] = AOs @ Wo^T; wave = 1m x 8n
    const unsigned short* Bb2 = Wpack + ((size_t)(wn * 8) * 64 + lane) * 8;
    const int arow = wm * 16 + sl;

    float4_t acc[8];
#pragma unroll
    for (int n = 0; n < 8; n++) acc[n] = (float4_t){0.f, 0.f, 0.f, 0.f};

#pragma unroll 1
    for (int kt = 0; kt < 16; ++kt) {
        short8 bfr[8];
#pragma unroll
        for (int n = 0; n < 8; n++)
            bfr[n] = *(const short8*)(Bb2 + (size_t)kt * 16384 + n * 512);
        int lslot = kt * 64 + g * 16;
        short8 a0 = *(const short8*)(AOs + arow * 1024 + (lslot ^ ((arow & 7) << 4)));
#pragma unroll
        for (int n = 0; n < 8; n++) acc[n] = MFMA(a0, bfr[n], acc[n]);
    }
    __syncthreads();  // all AOs reads done -> safe to overlay red

    // ---------------- epilogue: bias + residual, LN over the 512-col row, fp32 out
    float bias8[8], gc8[8], bc8[8];
#pragma unroll
    for (int n = 0; n < 8; n++) {
        int c = wn * 128 + n * 16 + sl;
        bias8[n] = bo[c]; gc8[n] = lng[c]; bc8[n] = lnb[c];
    }
#pragma unroll
    for (int j = 0; j < 4; j++) {
        int grow = T0 + wm * 16 + g * 4 + j;
        const float* xr = xres + (size_t)grow * 512;
#pragma unroll
        for (int n = 0; n < 8; n++)
            acc[n][j] += bias8[n] + xr[wn * 128 + n * 16 + sl];
    }
    // per-row partials over this wave's 128 cols; 16-lane butterfly; red[row][wn]
#pragma unroll
    for (int j = 0; j < 4; j++) {
        float s = 0.f, s2 = 0.f;
#pragma unroll
        for (int n = 0; n < 8; n++) { float v = acc[n][j]; s += v; s2 += v * v; }
#pragma unroll
        for (int mask = 1; mask < 16; mask <<= 1) {
            s += __shfl_xor(s, mask, 64);
            s2 += __shfl_xor(s2, mask, 64);
        }
        if (sl == 0) {
            int rl = wm * 16 + g * 4 + j;
            red[(rl * 4 + wn) * 2 + 0] = s;
            red[(rl * 4 + wn) * 2 + 1] = s2;
        }
    }
    __syncthreads();
#pragma unroll
    for (int j = 0; j < 4; j++) {
        int rl = wm * 16 + g * 4 + j;
        float s = 0.f, s2 = 0.f;
#pragma unroll
        for (int i = 0; i < 4; i++) {
            s += red[(rl * 4 + i) * 2 + 0];
            s2 += red[(rl * 4 + i) * 2 + 1];
        }
        float mu = s * (1.f / 512.f);
        float var = s2 * (1.f / 512.f) - mu * mu;
        float inv = rsqrtf(var + LN_EPS);
        float* yp = Y + (size_t)(T0 + rl) * 512;
#pragma unroll
        for (int n = 0; n < 8; n++) {
            int c = wn * 128 + n * 16 + sl;
            yp[c] = (acc[n][j] - mu) * inv * gc8[n] + bc8[n];
        }
    }
}

// ---------------------------------------------------------------- launch
extern "C" void kernel_launch(void* const* d_in, const int* in_sizes, int n_in,
                              void* d_out, int out_size, void* d_ws, size_t ws_size,
                              hipStream_t stream) {
    const float* x   = (const float*)d_in[0];
    const float* wq  = (const float*)d_in[1];
    const float* bq  = (const float*)d_in[2];
    const float* wk  = (const float*)d_in[3];
    const float* bk  = (const float*)d_in[4];
    const float* wv  = (const float*)d_in[5];
    const float* bv  = (const float*)d_in[6];
    const float* wo  = (const float*)d_in[7];
    const float* bo  = (const float*)d_in[8];
    const float* lng = (const float*)d_in[9];
    const float* lnb = (const float*)d_in[10];

    char* ws = (char*)d_ws;
    unsigned short* Xb    = (unsigned short*)(ws);                 //  67,108,864  x bf16
    unsigned short* Wqkv  = (unsigned short*)(ws + 67108864);      //   1,572,864  [1536,512] bf16
    unsigned short* Wpack = (unsigned short*)(ws + 68681728);      //     524,288  Wo packed bf16
    float*          Bqkv  = (float*)        (ws + 69206016);       //       6,144  [1536] f32
    unsigned short* QKV   = (unsigned short*)(ws + 69212160);      // 201,326,592  [N,1536] bf16
    float* Y = (float*)d_out;

    cast_x_kernel<<<2048, 256, 0, stream>>>(x, Xb, NTOK * 512 / 8);
    prep_w_kernel<<<1024, 256, 0, stream>>>(wq, wk, wv, wo, bq, bk, bv, Wqkv, Wpack, Bqkv);

    // QKV projection: [65536,512] x [1536,512]^T -> bf16 [65536,1536]
    gemm1_kernel<<<(NTOK / 256) * (QKVN / 256), 512, 0, stream>>>(Xb, Wqkv, Bqkv, QKV);

    // fused: per-token attention + O-proj + bias + residual + LayerNorm -> fp32 d_out
    attn_o_ln_kernel<<<NTOK / 32, 512, 0, stream>>>(QKV, Wpack, bo, x, lng, lnb, Y);
}

// Round 9
// 325.132 us; speedup vs baseline: 1.2622x; 1.0241x over previous
//
#include <hip/hip_runtime.h>
#include <stdint.h>

#define NTOK 65536     // B*S = 16*4096
#define DMODEL 512
#define QKVN 1536
#define LN_EPS 1e-5f

typedef __attribute__((ext_vector_type(8))) short short8;
typedef __attribute__((ext_vector_type(8))) unsigned short ushort8;
typedef __attribute__((ext_vector_type(4))) float float4_t;
typedef __attribute__((ext_vector_type(4))) unsigned int uint4_t;

static __device__ __forceinline__ float bf2f(unsigned short u) {
    union { unsigned int i; float f; } c; c.i = ((unsigned int)u) << 16; return c.f;
}
static __device__ __forceinline__ unsigned short f2bf(float f) {
    union { float f; unsigned int i; } c; c.f = f;
    unsigned int x = c.i;
    return (unsigned short)((x + 0x7fffu + ((x >> 16) & 1u)) >> 16);  // RNE
}
static __device__ __forceinline__ unsigned int cvt_pk_bf16(float lo, float hi) {
    unsigned int r;
    asm("v_cvt_pk_bf16_f32 %0, %1, %2" : "=v"(r) : "v"(lo), "v"(hi));
    return r;
}
static __device__ __forceinline__ void gload_lds16(const void* g, void* l) {
    __builtin_amdgcn_global_load_lds((const __attribute__((address_space(1))) void*)g,
                                     (__attribute__((address_space(3))) void*)l, 16, 0, 0);
}

#define BAR() __builtin_amdgcn_s_barrier()
#define WAITL0() asm volatile("s_waitcnt lgkmcnt(0)" ::: "memory")
#define WVM(n) asm volatile("s_waitcnt vmcnt(" #n ")" ::: "memory")
#define MFMA(a, b, c) __builtin_amdgcn_mfma_f32_16x16x32_bf16((a), (b), (c), 0, 0, 0)

// ---------------------------------------------------------------- prep: cast x to bf16
__global__ __launch_bounds__(256) void cast_x_kernel(const float* __restrict__ x,
                                                     unsigned short* __restrict__ xb, int n8) {
    int stride = gridDim.x * blockDim.x;
    for (int i = blockIdx.x * blockDim.x + threadIdx.x; i < n8; i += stride) {
        const float4_t* p = (const float4_t*)(x + (size_t)i * 8);
        float4_t a = p[0], b = p[1];
        ushort8 v;
        v[0] = f2bf(a[0]); v[1] = f2bf(a[1]); v[2] = f2bf(a[2]); v[3] = f2bf(a[3]);
        v[4] = f2bf(b[0]); v[5] = f2bf(b[1]); v[6] = f2bf(b[2]); v[7] = f2bf(b[3]);
        *(ushort8*)(xb + (size_t)i * 8) = v;
    }
}

// ---------------------------------------------------------------- prep: weights + bias
// Wqkv: [1536,512] bf16 row-major.  Wpack: Wo in MFMA-fragment order:
// Wpack[((kt*32 + nf)*64 + lane)*8 + e] = Wo[nf*16 + (lane&15)][kt*32 + (lane>>4)*8 + e]
__global__ __launch_bounds__(256) void prep_w_kernel(
    const float* __restrict__ wq, const float* __restrict__ wk, const float* __restrict__ wv,
    const float* __restrict__ wo,
    const float* __restrict__ bq, const float* __restrict__ bk, const float* __restrict__ bv,
    unsigned short* __restrict__ wqkv, unsigned short* __restrict__ wpack,
    float* __restrict__ bias_qkv) {
    const int WN = DMODEL * DMODEL;  // 262144
    int tid = blockIdx.x * blockDim.x + threadIdx.x;
    int stride = gridDim.x * blockDim.x;
    for (int j = tid; j < 3 * WN; j += stride) {
        int seg = j / WN, idx = j - seg * WN;
        const float* src = (seg == 0) ? wq : (seg == 1) ? wk : wv;
        wqkv[j] = f2bf(src[idx]);
    }
    for (int j = tid; j < WN; j += stride) {
        int e = j & 7, l = (j >> 3) & 63, nf = (j >> 9) & 31, kt = j >> 14;
        int row = nf * 16 + (l & 15);
        int k = kt * 32 + ((l >> 4) << 3) + e;
        wpack[j] = f2bf(wo[row * 512 + k]);
    }
    for (int j = tid; j < QKVN; j += stride)
        bias_qkv[j] = (j < 512) ? bq[j] : (j < 1024) ? bk[j - 512] : bv[j - 1024];
}

// ---------------------------------------------------------------- GEMM1: QKV = Xb @ Wqkv^T + bias
// 256x256 tile, BK=32, 8 waves (2x4), 4-slot circular LDS pipeline (128 KB),
// counted vmcnt (never 0 in steady state), XOR-swizzled LDS, XCD block swizzle.
__global__ __launch_bounds__(512, 2) void gemm1_kernel(
    const unsigned short* __restrict__ A, const unsigned short* __restrict__ Bw,
    const float* __restrict__ bias, unsigned short* __restrict__ Cout) {
    __shared__ unsigned short As[4][256 * 32];  // 64 KB
    __shared__ unsigned short Bs[4][256 * 32];  // 64 KB

    const int b = blockIdx.x;                   // grid = 1536 = 8 * 192
    const int L = (b & 7) * 192 + (b >> 3);     // bijective XCD swizzle
    const int bm = L / 6;
    const int bn = L - bm * 6;

    const int t = threadIdx.x;
    const int lane = t & 63;
    const int w = t >> 6;
    const int wm = w >> 2, wn = w & 3;          // 2 x 4 waves

    const unsigned short* Ab = A + (size_t)bm * 256 * 512;
    const unsigned short* Bb = Bw + (size_t)bn * 256 * 512;

    // staging addressing: LDS linear dest, global source inverse-swizzled
    const int i0 = t, i1 = 512 + t;
    const int r0 = i0 >> 2, s0 = (i0 & 3) ^ ((r0 >> 1) & 3);
    const int r1 = i1 >> 2, s1 = (i1 & 3) ^ ((r1 >> 1) & 3);

#define STAGE_A1(kt) do { \
        gload_lds16(Ab + r0 * 512 + (kt) * 32 + s0 * 8, &As[(kt) & 3][i0 * 8]); \
        gload_lds16(Ab + r1 * 512 + (kt) * 32 + s1 * 8, &As[(kt) & 3][i1 * 8]); } while (0)
#define STAGE_B1(kt) do { \
        gload_lds16(Bb + r0 * 512 + (kt) * 32 + s0 * 8, &Bs[(kt) & 3][i0 * 8]); \
        gload_lds16(Bb + r1 * 512 + (kt) * 32 + s1 * 8, &Bs[(kt) & 3][i1 * 8]); } while (0)

    // fragment read offsets (swizzled): p = (lane>>4) ^ ((row>>1)&3)
    int aoff[8], boff[4];
#pragma unroll
    for (int m = 0; m < 8; m++) {
        int row = wm * 128 + m * 16 + (lane & 15);
        aoff[m] = row * 32 + (((lane >> 4) ^ ((row >> 1) & 3)) * 8);
    }
#pragma unroll
    for (int n = 0; n < 4; n++) {
        int row = wn * 64 + n * 16 + (lane & 15);
        boff[n] = row * 32 + (((lane >> 4) ^ ((row >> 1) & 3)) * 8);
    }

    float4_t acc[8][4];
#pragma unroll
    for (int m = 0; m < 8; m++)
#pragma unroll
        for (int n = 0; n < 4; n++) acc[m][n] = (float4_t){0.f, 0.f, 0.f, 0.f};

    // prologue: stage K-tiles 0,1,2 (12 loads); wait tile 0 (8 remain in flight)
    STAGE_A1(0); STAGE_B1(0);
    STAGE_A1(1); STAGE_B1(1);
    STAGE_A1(2); STAGE_B1(2);
    WVM(8);
    BAR();

    short8 ar[8], br[4];
#pragma unroll
    for (int kt = 0; kt < 16; ++kt) {
        const int sl = kt & 3;
        // ---- phase 0: read A frags + B n0/n1, stage A of kt+3, MFMA n-half 0
#pragma unroll
        for (int m = 0; m < 8; m++) ar[m] = *(const short8*)&As[sl][aoff[m]];
        br[0] = *(const short8*)&Bs[sl][boff[0]];
        br[1] = *(const short8*)&Bs[sl][boff[1]];
        if (kt <= 12) STAGE_A1(kt + 3);
        BAR();
        WAITL0();
        __builtin_amdgcn_s_setprio(1);
#pragma unroll
        for (int m = 0; m < 8; m++) {
            acc[m][0] = MFMA(ar[m], br[0], acc[m][0]);
            acc[m][1] = MFMA(ar[m], br[1], acc[m][1]);
        }
        __builtin_amdgcn_s_setprio(0);
        BAR();
        // ---- phase 1: read B n2/n3, stage B of kt+3, MFMA n-half 1
        br[2] = *(const short8*)&Bs[sl][boff[2]];
        br[3] = *(const short8*)&Bs[sl][boff[3]];
        if (kt <= 12) STAGE_B1(kt + 3);
        BAR();
        WAITL0();
        __builtin_amdgcn_s_setprio(1);
#pragma unroll
        for (int m = 0; m < 8; m++) {
            acc[m][2] = MFMA(ar[m], br[2], acc[m][2]);
            acc[m][3] = MFMA(ar[m], br[3], acc[m][3]);
        }
        __builtin_amdgcn_s_setprio(0);
        // K-tile boundary: ensure tile kt+1 landed; keep 2 tiles (8 loads) in flight
        if (kt <= 12) { WVM(8); }
        else if (kt == 13) { WVM(4); }
        else if (kt == 14) { WVM(0); }
        BAR();
    }

    // ---- epilogue: C/D mapping col=lane&15, row=(lane>>4)*4+j
    const int orow0 = bm * 256 + wm * 128;
    const int ocol0 = bn * 256 + wn * 64;
#pragma unroll
    for (int m = 0; m < 8; m++) {
#pragma unroll
        for (int n = 0; n < 4; n++) {
            int col = ocol0 + n * 16 + (lane & 15);
            float bv = bias[col];
#pragma unroll
            for (int j = 0; j < 4; j++) {
                int row = orow0 + m * 16 + (lane >> 4) * 4 + j;
                Cout[(size_t)row * QKVN + col] = f2bf(acc[m][n][j] + bv);
            }
        }
    }
#undef STAGE_A1
#undef STAGE_B1
}

// ---------------------------------------------------------------- FUSED: attention + O-proj + residual + LN
// Block = 32 tokens, 512 threads = 8 waves (2m x 4n), 16 waves/CU.
// Phase 1: per-token QKV loaded ONCE into regs (12 x short8), per-head
//          in-register attention, AO -> XOR-swizzled LDS (32 KB).
// Phase 2: distance-1 software pipeline on B (two named buffers, 2 kt/iter);
//          A from swizzled LDS. acc = 8 frags (32 regs).
// Epilogue: bias + resid + full-row LN; red overlaid on AOs.
__global__ __launch_bounds__(512, 4) void attn_o_ln_kernel(
    const unsigned short* __restrict__ qkv, const unsigned short* __restrict__ Wpack,
    const float* __restrict__ bo, const float* __restrict__ xres,
    const float* __restrict__ lng, const float* __restrict__ lnb,
    float* __restrict__ Y) {
    __shared__ __align__(16) unsigned char AOs[32 * 1024];  // 32 rows x 512 bf16, swizzled
    float* red = (float*)AOs;                               // overlaid after phase 2

    const int T0 = blockIdx.x * 32;
    const int t = threadIdx.x;
    const int lane = t & 63;
    const int w = t >> 6;        // wave id 0..7
    const int g = lane >> 4;     // token subgroup 0..3
    const int sl = lane & 15;    // dim-slice owner: dims [8*sl, 8*sl+8)
    const int wm = w >> 2;       // m-half 0..1
    const int wn = w & 3;        // n-quarter 0..3

    const float scale = 0.08838834764831845f;  // 1/sqrt(128)

    // ---------------- phase 1: load QKV once, per-head attention (tr = w*4+g)
    {
        const int tr = w * 4 + g;  // LDS row / relative token
        const unsigned short* base = qkv + (size_t)(T0 + tr) * QKVN + sl * 8;

        short8 qr[4], kr[4], vr[4];  // 48 VGPRs, held across the h-loop
#pragma unroll
        for (int h = 0; h < 4; h++) {
            qr[h] = *(const short8*)(base + h * 128);
            kr[h] = *(const short8*)(base + 512 + h * 128);
            vr[h] = *(const short8*)(base + 1024 + h * 128);
        }
#pragma unroll
        for (int h = 0; h < 4; h++) {
            float qf[8];
#pragma unroll
            for (int d = 0; d < 8; d++) qf[d] = bf2f((unsigned short)qr[h][d]);
            float s[4];
#pragma unroll
            for (int tt = 0; tt < 4; tt++) {
                float a0 = 0.f;
#pragma unroll
                for (int d = 0; d < 8; d++) a0 += qf[d] * bf2f((unsigned short)kr[tt][d]);
                s[tt] = a0;
            }
#pragma unroll
            for (int mask = 1; mask < 16; mask <<= 1)
#pragma unroll
                for (int tt = 0; tt < 4; tt++)
                    s[tt] += __shfl_xor(s[tt], mask, 64);
            float m0 = fmaxf(fmaxf(s[0], s[1]), fmaxf(s[2], s[3])) * scale;
            float p[4];
            float sum = 0.f;
#pragma unroll
            for (int tt = 0; tt < 4; tt++) { p[tt] = __expf(s[tt] * scale - m0); sum += p[tt]; }
            float rr = __frcp_rn(sum);
            float o[8];
#pragma unroll
            for (int d = 0; d < 8; d++) o[d] = 0.f;
#pragma unroll
            for (int tt = 0; tt < 4; tt++) {
                float ph = p[tt] * rr;
#pragma unroll
                for (int d = 0; d < 8; d++) o[d] += ph * bf2f((unsigned short)vr[tt][d]);
            }
            uint4_t pk;
            pk[0] = cvt_pk_bf16(o[0], o[1]);
            pk[1] = cvt_pk_bf16(o[2], o[3]);
            pk[2] = cvt_pk_bf16(o[4], o[5]);
            pk[3] = cvt_pk_bf16(o[6], o[7]);
            int off = tr * 1024 + ((h * 256 + sl * 16) ^ ((tr & 7) << 4));
            *(uint4_t*)(AOs + off) = pk;
        }
    }
    __syncthreads();

    // ---------------- phase 2: [32x512] = AOs @ Wo^T; wave = 1m x 8n;
    // distance-1 pipeline: two named B buffers, 2 kt per iteration.
    const unsigned short* Bb2 = Wpack + ((size_t)(wn * 8) * 64 + lane) * 8;
    const int arow = wm * 16 + sl;
    const int aswz = (arow & 7) << 4;

    float4_t acc[8];
#pragma unroll
    for (int n = 0; n < 8; n++) acc[n] = (float4_t){0.f, 0.f, 0.f, 0.f};

    short8 bA[8], bB[8];
#pragma unroll
    for (int n = 0; n < 8; n++) bA[n] = *(const short8*)(Bb2 + n * 512);
#pragma unroll
    for (int n = 0; n < 8; n++) bB[n] = *(const short8*)(Bb2 + 16384 + n * 512);

#pragma unroll 1
    for (int kt = 0; kt < 16; kt += 2) {
        // even kt: consume bA, prefetch kt+2 into bA
        short8 a0 = *(const short8*)(AOs + arow * 1024 + ((kt * 64 + g * 16) ^ aswz));
#pragma unroll
        for (int n = 0; n < 8; n++) acc[n] = MFMA(a0, bA[n], acc[n]);
        if (kt + 2 < 16) {
#pragma unroll
            for (int n = 0; n < 8; n++)
                bA[n] = *(const short8*)(Bb2 + (size_t)(kt + 2) * 16384 + n * 512);
        }
        // odd kt+1: consume bB, prefetch kt+3 into bB
        short8 a1 = *(const short8*)(AOs + arow * 1024 + (((kt + 1) * 64 + g * 16) ^ aswz));
#pragma unroll
        for (int n = 0; n < 8; n++) acc[n] = MFMA(a1, bB[n], acc[n]);
        if (kt + 3 < 16) {
#pragma unroll
            for (int n = 0; n < 8; n++)
                bB[n] = *(const short8*)(Bb2 + (size_t)(kt + 3) * 16384 + n * 512);
        }
    }
    __syncthreads();  // all AOs reads done -> safe to overlay red

    // ---------------- epilogue: bias + residual, LN over the 512-col row, fp32 out
    float bias8[8], gc8[8], bc8[8];
#pragma unroll
    for (int n = 0; n < 8; n++) {
        int c = wn * 128 + n * 16 + sl;
        bias8[n] = bo[c]; gc8[n] = lng[c]; bc8[n] = lnb[c];
    }
#pragma unroll
    for (int j = 0; j < 4; j++) {
        int grow = T0 + wm * 16 + g * 4 + j;
        const float* xr = xres + (size_t)grow * 512;
#pragma unroll
        for (int n = 0; n < 8; n++)
            acc[n][j] += bias8[n] + xr[wn * 128 + n * 16 + sl];
    }
    // per-row partials over this wave's 128 cols; 16-lane butterfly; red[row][wn]
#pragma unroll
    for (int j = 0; j < 4; j++) {
        float s = 0.f, s2 = 0.f;
#pragma unroll
        for (int n = 0; n < 8; n++) { float v = acc[n][j]; s += v; s2 += v * v; }
#pragma unroll
        for (int mask = 1; mask < 16; mask <<= 1) {
            s += __shfl_xor(s, mask, 64);
            s2 += __shfl_xor(s2, mask, 64);
        }
        if (sl == 0) {
            int rl = wm * 16 + g * 4 + j;
            red[(rl * 4 + wn) * 2 + 0] = s;
            red[(rl * 4 + wn) * 2 + 1] = s2;
        }
    }
    __syncthreads();
#pragma unroll
    for (int j = 0; j < 4; j++) {
        int rl = wm * 16 + g * 4 + j;
        float s = 0.f, s2 = 0.f;
#pragma unroll
        for (int i = 0; i < 4; i++) {
            s += red[(rl * 4 + i) * 2 + 0];
            s2 += red[(rl * 4 + i) * 2 + 1];
        }
        float mu = s * (1.f / 512.f);
        float var = s2 * (1.f / 512.f) - mu * mu;
        float inv = rsqrtf(var + LN_EPS);
        float* yp = Y + (size_t)(T0 + rl) * 512;
#pragma unroll
        for (int n = 0; n < 8; n++) {
            int c = wn * 128 + n * 16 + sl;
            yp[c] = (acc[n][j] - mu) * inv * gc8[n] + bc8[n];
        }
    }
}

// ---------------------------------------------------------------- launch
extern "C" void kernel_launch(void* const* d_in, const int* in_sizes, int n_in,
                              void* d_out, int out_size, void* d_ws, size_t ws_size,
                              hipStream_t stream) {
    const float* x   = (const float*)d_in[0];
    const float* wq  = (const float*)d_in[1];
    const float* bq  = (const float*)d_in[2];
    const float* wk  = (const float*)d_in[3];
    const float* bk  = (const float*)d_in[4];
    const float* wv  = (const float*)d_in[5];
    const float* bv  = (const float*)d_in[6];
    const float* wo  = (const float*)d_in[7];
    const float* bo  = (const float*)d_in[8];
    const float* lng = (const float*)d_in[9];
    const float* lnb = (const float*)d_in[10];

    char* ws = (char*)d_ws;
    unsigned short* Xb    = (unsigned short*)(ws);                 //  67,108,864  x bf16
    unsigned short* Wqkv  = (unsigned short*)(ws + 67108864);      //   1,572,864  [1536,512] bf16
    unsigned short* Wpack = (unsigned short*)(ws + 68681728);      //     524,288  Wo packed bf16
    float*          Bqkv  = (float*)        (ws + 69206016);       //       6,144  [1536] f32
    unsigned short* QKV   = (unsigned short*)(ws + 69212160);      // 201,326,592  [N,1536] bf16
    float* Y = (float*)d_out;

    cast_x_kernel<<<2048, 256, 0, stream>>>(x, Xb, NTOK * 512 / 8);
    prep_w_kernel<<<1024, 256, 0, stream>>>(wq, wk, wv, wo, bq, bk, bv, Wqkv, Wpack, Bqkv);

    // QKV projection: [65536,512] x [1536,512]^T -> bf16 [65536,1536]
    gemm1_kernel<<<(NTOK / 256) * (QKVN / 256), 512, 0, stream>>>(Xb, Wqkv, Bqkv, QKV);

    // fused: per-token attention + O-proj + bias + residual + LayerNorm -> fp32 d_out
    attn_o_ln_kernel<<<NTOK / 32, 512, 0, stream>>>(QKV, Wpack, bo, x, lng, lnb, Y);
}

// Round 10
// 323.298 us; speedup vs baseline: 1.2693x; 1.0057x over previous
//
#include <hip/hip_runtime.h>
#include <stdint.h>

#define NTOK 65536     // B*S = 16*4096
#define DMODEL 512
#define QKVN 1536
#define LN_EPS 1e-5f

typedef __attribute__((ext_vector_type(8))) short short8;
typedef __attribute__((ext_vector_type(8))) unsigned short ushort8;
typedef __attribute__((ext_vector_type(4))) float float4_t;
typedef __attribute__((ext_vector_type(4))) unsigned int uint4_t;

static __device__ __forceinline__ float bf2f(unsigned short u) {
    union { unsigned int i; float f; } c; c.i = ((unsigned int)u) << 16; return c.f;
}
static __device__ __forceinline__ unsigned short f2bf(float f) {
    union { float f; unsigned int i; } c; c.f = f;
    unsigned int x = c.i;
    return (unsigned short)((x + 0x7fffu + ((x >> 16) & 1u)) >> 16);  // RNE
}
static __device__ __forceinline__ unsigned int cvt_pk_bf16(float lo, float hi) {
    unsigned int r;
    asm("v_cvt_pk_bf16_f32 %0, %1, %2" : "=v"(r) : "v"(lo), "v"(hi));
    return r;
}
static __device__ __forceinline__ void gload_lds16(const void* g, void* l) {
    __builtin_amdgcn_global_load_lds((const __attribute__((address_space(1))) void*)g,
                                     (__attribute__((address_space(3))) void*)l, 16, 0, 0);
}

#define BAR() __builtin_amdgcn_s_barrier()
#define WAITL0() asm volatile("s_waitcnt lgkmcnt(0)" ::: "memory")
#define WVM(n) asm volatile("s_waitcnt vmcnt(" #n ")" ::: "memory")
#define MFMA(a, b, c) __builtin_amdgcn_mfma_f32_16x16x32_bf16((a), (b), (c), 0, 0, 0)

// ---------------------------------------------------------------- prep: cast x to bf16
__global__ __launch_bounds__(256) void cast_x_kernel(const float* __restrict__ x,
                                                     unsigned short* __restrict__ xb, int n8) {
    int stride = gridDim.x * blockDim.x;
    for (int i = blockIdx.x * blockDim.x + threadIdx.x; i < n8; i += stride) {
        const float4_t* p = (const float4_t*)(x + (size_t)i * 8);
        float4_t a = p[0], b = p[1];
        ushort8 v;
        v[0] = f2bf(a[0]); v[1] = f2bf(a[1]); v[2] = f2bf(a[2]); v[3] = f2bf(a[3]);
        v[4] = f2bf(b[0]); v[5] = f2bf(b[1]); v[6] = f2bf(b[2]); v[7] = f2bf(b[3]);
        *(ushort8*)(xb + (size_t)i * 8) = v;
    }
}

// ---------------------------------------------------------------- prep: weights + bias
// Wqkv: [1536,512] bf16 row-major.  Wpack: Wo in MFMA-fragment order:
// Wpack[((kt*32 + nf)*64 + lane)*8 + e] = Wo[nf*16 + (lane&15)][kt*32 + (lane>>4)*8 + e]
__global__ __launch_bounds__(256) void prep_w_kernel(
    const float* __restrict__ wq, const float* __restrict__ wk, const float* __restrict__ wv,
    const float* __restrict__ wo,
    const float* __restrict__ bq, const float* __restrict__ bk, const float* __restrict__ bv,
    unsigned short* __restrict__ wqkv, unsigned short* __restrict__ wpack,
    float* __restrict__ bias_qkv) {
    const int WN = DMODEL * DMODEL;  // 262144
    int tid = blockIdx.x * blockDim.x + threadIdx.x;
    int stride = gridDim.x * blockDim.x;
    for (int j = tid; j < 3 * WN; j += stride) {
        int seg = j / WN, idx = j - seg * WN;
        const float* src = (seg == 0) ? wq : (seg == 1) ? wk : wv;
        wqkv[j] = f2bf(src[idx]);
    }
    for (int j = tid; j < WN; j += stride) {
        int e = j & 7, l = (j >> 3) & 63, nf = (j >> 9) & 31, kt = j >> 14;
        int row = nf * 16 + (l & 15);
        int k = kt * 32 + ((l >> 4) << 3) + e;
        wpack[j] = f2bf(wo[row * 512 + k]);
    }
    for (int j = tid; j < QKVN; j += stride)
        bias_qkv[j] = (j < 512) ? bq[j] : (j < 1024) ? bk[j - 512] : bv[j - 1024];
}

// ---------------------------------------------------------------- GEMM1: QKV = Xb @ Wqkv^T + bias
// 256x256 tile, BK=32, 8 waves (2x4), 4-slot circular LDS pipeline (128 KB),
// counted vmcnt (never 0 in steady state), XOR-swizzled LDS, XCD block swizzle.
__global__ __launch_bounds__(512, 2) void gemm1_kernel(
    const unsigned short* __restrict__ A, const unsigned short* __restrict__ Bw,
    const float* __restrict__ bias, unsigned short* __restrict__ Cout) {
    __shared__ unsigned short As[4][256 * 32];  // 64 KB
    __shared__ unsigned short Bs[4][256 * 32];  // 64 KB

    const int b = blockIdx.x;                   // grid = 1536 = 8 * 192
    const int L = (b & 7) * 192 + (b >> 3);     // bijective XCD swizzle
    const int bm = L / 6;
    const int bn = L - bm * 6;

    const int t = threadIdx.x;
    const int lane = t & 63;
    const int w = t >> 6;
    const int wm = w >> 2, wn = w & 3;          // 2 x 4 waves

    const unsigned short* Ab = A + (size_t)bm * 256 * 512;
    const unsigned short* Bb = Bw + (size_t)bn * 256 * 512;

    // staging addressing: LDS linear dest, global source inverse-swizzled
    const int i0 = t, i1 = 512 + t;
    const int r0 = i0 >> 2, s0 = (i0 & 3) ^ ((r0 >> 1) & 3);
    const int r1 = i1 >> 2, s1 = (i1 & 3) ^ ((r1 >> 1) & 3);

#define STAGE_A1(kt) do { \
        gload_lds16(Ab + r0 * 512 + (kt) * 32 + s0 * 8, &As[(kt) & 3][i0 * 8]); \
        gload_lds16(Ab + r1 * 512 + (kt) * 32 + s1 * 8, &As[(kt) & 3][i1 * 8]); } while (0)
#define STAGE_B1(kt) do { \
        gload_lds16(Bb + r0 * 512 + (kt) * 32 + s0 * 8, &Bs[(kt) & 3][i0 * 8]); \
        gload_lds16(Bb + r1 * 512 + (kt) * 32 + s1 * 8, &Bs[(kt) & 3][i1 * 8]); } while (0)

    // fragment read offsets (swizzled): p = (lane>>4) ^ ((row>>1)&3)
    int aoff[8], boff[4];
#pragma unroll
    for (int m = 0; m < 8; m++) {
        int row = wm * 128 + m * 16 + (lane & 15);
        aoff[m] = row * 32 + (((lane >> 4) ^ ((row >> 1) & 3)) * 8);
    }
#pragma unroll
    for (int n = 0; n < 4; n++) {
        int row = wn * 64 + n * 16 + (lane & 15);
        boff[n] = row * 32 + (((lane >> 4) ^ ((row >> 1) & 3)) * 8);
    }

    float4_t acc[8][4];
#pragma unroll
    for (int m = 0; m < 8; m++)
#pragma unroll
        for (int n = 0; n < 4; n++) acc[m][n] = (float4_t){0.f, 0.f, 0.f, 0.f};

    // prologue: stage K-tiles 0,1,2 (12 loads); wait tile 0 (8 remain in flight)
    STAGE_A1(0); STAGE_B1(0);
    STAGE_A1(1); STAGE_B1(1);
    STAGE_A1(2); STAGE_B1(2);
    WVM(8);
    BAR();

    short8 ar[8], br[4];
#pragma unroll
    for (int kt = 0; kt < 16; ++kt) {
        const int sl = kt & 3;
        // ---- phase 0: read A frags + B n0/n1, stage A of kt+3, MFMA n-half 0
#pragma unroll
        for (int m = 0; m < 8; m++) ar[m] = *(const short8*)&As[sl][aoff[m]];
        br[0] = *(const short8*)&Bs[sl][boff[0]];
        br[1] = *(const short8*)&Bs[sl][boff[1]];
        if (kt <= 12) STAGE_A1(kt + 3);
        BAR();
        WAITL0();
        __builtin_amdgcn_s_setprio(1);
#pragma unroll
        for (int m = 0; m < 8; m++) {
            acc[m][0] = MFMA(ar[m], br[0], acc[m][0]);
            acc[m][1] = MFMA(ar[m], br[1], acc[m][1]);
        }
        __builtin_amdgcn_s_setprio(0);
        BAR();
        // ---- phase 1: read B n2/n3, stage B of kt+3, MFMA n-half 1
        br[2] = *(const short8*)&Bs[sl][boff[2]];
        br[3] = *(const short8*)&Bs[sl][boff[3]];
        if (kt <= 12) STAGE_B1(kt + 3);
        BAR();
        WAITL0();
        __builtin_amdgcn_s_setprio(1);
#pragma unroll
        for (int m = 0; m < 8; m++) {
            acc[m][2] = MFMA(ar[m], br[2], acc[m][2]);
            acc[m][3] = MFMA(ar[m], br[3], acc[m][3]);
        }
        __builtin_amdgcn_s_setprio(0);
        // K-tile boundary: ensure tile kt+1 landed; keep 2 tiles (8 loads) in flight
        if (kt <= 12) { WVM(8); }
        else if (kt == 13) { WVM(4); }
        else if (kt == 14) { WVM(0); }
        BAR();
    }

    // ---- epilogue: C/D mapping col=lane&15, row=(lane>>4)*4+j
    const int orow0 = bm * 256 + wm * 128;
    const int ocol0 = bn * 256 + wn * 64;
#pragma unroll
    for (int m = 0; m < 8; m++) {
#pragma unroll
        for (int n = 0; n < 4; n++) {
            int col = ocol0 + n * 16 + (lane & 15);
            float bv = bias[col];
#pragma unroll
            for (int j = 0; j < 4; j++) {
                int row = orow0 + m * 16 + (lane >> 4) * 4 + j;
                Cout[(size_t)row * QKVN + col] = f2bf(acc[m][n][j] + bv);
            }
        }
    }
#undef STAGE_A1
#undef STAGE_B1
}

// ---------------------------------------------------------------- FUSED: attention + O-proj + residual + LN
// Block = 16 tokens, 256 threads = 4 waves, 16 KB LDS -> ~5 blocks/CU
// (5 independent barrier groups: phase diversity hides barrier/VALU phases).
// Phase 1: QKV loaded once (12 x short8), per-head in-register attention,
//          AO -> XOR-swizzled LDS (16 rows x 1 KB).
// Phase 2: wave = 1 m-frag x 8 n-frags (acc 32 regs); A from LDS,
//          B distance-1 pipelined from Wpack (L2-resident).
// Epilogue: bias + resid + full-row LN; red overlaid on AOs.
__global__ __launch_bounds__(256, 4) void attn_o_ln_kernel(
    const unsigned short* __restrict__ qkv, const unsigned short* __restrict__ Wpack,
    const float* __restrict__ bo, const float* __restrict__ xres,
    const float* __restrict__ lng, const float* __restrict__ lnb,
    float* __restrict__ Y) {
    __shared__ __align__(16) unsigned char AOs[16 * 1024];  // 16 rows x 512 bf16, swizzled
    float* red = (float*)AOs;                               // overlaid after phase 2

    const int T0 = blockIdx.x * 16;
    const int t = threadIdx.x;
    const int lane = t & 63;
    const int w = t >> 6;        // wave id 0..3 (n-quarter)
    const int g = lane >> 4;     // token subgroup / k-slice 0..3
    const int sl = lane & 15;    // dim-slice owner: dims [8*sl, 8*sl+8)

    const float scale = 0.08838834764831845f;  // 1/sqrt(128)

    // ---------------- phase 1: load QKV once, per-head attention (tr = w*4+g)
    {
        const int tr = w * 4 + g;  // LDS row / relative token, 0..15
        const unsigned short* base = qkv + (size_t)(T0 + tr) * QKVN + sl * 8;

        short8 qr[4], kr[4], vr[4];  // 48 VGPRs, held across the h-loop
#pragma unroll
        for (int h = 0; h < 4; h++) {
            qr[h] = *(const short8*)(base + h * 128);
            kr[h] = *(const short8*)(base + 512 + h * 128);
            vr[h] = *(const short8*)(base + 1024 + h * 128);
        }
#pragma unroll
        for (int h = 0; h < 4; h++) {
            float qf[8];
#pragma unroll
            for (int d = 0; d < 8; d++) qf[d] = bf2f((unsigned short)qr[h][d]);
            float s[4];
#pragma unroll
            for (int tt = 0; tt < 4; tt++) {
                float a0 = 0.f;
#pragma unroll
                for (int d = 0; d < 8; d++) a0 += qf[d] * bf2f((unsigned short)kr[tt][d]);
                s[tt] = a0;
            }
#pragma unroll
            for (int mask = 1; mask < 16; mask <<= 1)
#pragma unroll
                for (int tt = 0; tt < 4; tt++)
                    s[tt] += __shfl_xor(s[tt], mask, 64);
            float m0 = fmaxf(fmaxf(s[0], s[1]), fmaxf(s[2], s[3])) * scale;
            float p[4];
            float sum = 0.f;
#pragma unroll
            for (int tt = 0; tt < 4; tt++) { p[tt] = __expf(s[tt] * scale - m0); sum += p[tt]; }
            float rr = __frcp_rn(sum);
            float o[8];
#pragma unroll
            for (int d = 0; d < 8; d++) o[d] = 0.f;
#pragma unroll
            for (int tt = 0; tt < 4; tt++) {
                float ph = p[tt] * rr;
#pragma unroll
                for (int d = 0; d < 8; d++) o[d] += ph * bf2f((unsigned short)vr[tt][d]);
            }
            uint4_t pk;
            pk[0] = cvt_pk_bf16(o[0], o[1]);
            pk[1] = cvt_pk_bf16(o[2], o[3]);
            pk[2] = cvt_pk_bf16(o[4], o[5]);
            pk[3] = cvt_pk_bf16(o[6], o[7]);
            int off = tr * 1024 + ((h * 256 + sl * 16) ^ ((tr & 7) << 4));
            *(uint4_t*)(AOs + off) = pk;
        }
    }
    __syncthreads();

    // ---------------- phase 2: [16x512] = AOs @ Wo^T; wave = 1m x 8n;
    // distance-1 pipeline: two named B buffers, 2 kt per iteration.
    const unsigned short* Bb2 = Wpack + ((size_t)(w * 8) * 64 + lane) * 8;
    const int arow = sl;                 // MFMA A row = lane&15
    const int aswz = (arow & 7) << 4;

    float4_t acc[8];
#pragma unroll
    for (int n = 0; n < 8; n++) acc[n] = (float4_t){0.f, 0.f, 0.f, 0.f};

    short8 bA[8], bB[8];
#pragma unroll
    for (int n = 0; n < 8; n++) bA[n] = *(const short8*)(Bb2 + n * 512);
#pragma unroll
    for (int n = 0; n < 8; n++) bB[n] = *(const short8*)(Bb2 + 16384 + n * 512);

#pragma unroll 1
    for (int kt = 0; kt < 16; kt += 2) {
        // even kt: consume bA, prefetch kt+2 into bA
        short8 a0 = *(const short8*)(AOs + arow * 1024 + ((kt * 64 + g * 16) ^ aswz));
#pragma unroll
        for (int n = 0; n < 8; n++) acc[n] = MFMA(a0, bA[n], acc[n]);
        if (kt + 2 < 16) {
#pragma unroll
            for (int n = 0; n < 8; n++)
                bA[n] = *(const short8*)(Bb2 + (size_t)(kt + 2) * 16384 + n * 512);
        }
        // odd kt+1: consume bB, prefetch kt+3 into bB
        short8 a1 = *(const short8*)(AOs + arow * 1024 + (((kt + 1) * 64 + g * 16) ^ aswz));
#pragma unroll
        for (int n = 0; n < 8; n++) acc[n] = MFMA(a1, bB[n], acc[n]);
        if (kt + 3 < 16) {
#pragma unroll
            for (int n = 0; n < 8; n++)
                bB[n] = *(const short8*)(Bb2 + (size_t)(kt + 3) * 16384 + n * 512);
        }
    }
    __syncthreads();  // all AOs reads done -> safe to overlay red

    // ---------------- epilogue: bias + residual, LN over the 512-col row, fp32 out
    float bias8[8], gc8[8], bc8[8];
#pragma unroll
    for (int n = 0; n < 8; n++) {
        int c = w * 128 + n * 16 + sl;
        bias8[n] = bo[c]; gc8[n] = lng[c]; bc8[n] = lnb[c];
    }
#pragma unroll
    for (int j = 0; j < 4; j++) {
        int grow = T0 + g * 4 + j;
        const float* xr = xres + (size_t)grow * 512;
#pragma unroll
        for (int n = 0; n < 8; n++)
            acc[n][j] += bias8[n] + xr[w * 128 + n * 16 + sl];
    }
    // per-row partials over this wave's 128 cols; 16-lane butterfly; red[row][w]
#pragma unroll
    for (int j = 0; j < 4; j++) {
        float s = 0.f, s2 = 0.f;
#pragma unroll
        for (int n = 0; n < 8; n++) { float v = acc[n][j]; s += v; s2 += v * v; }
#pragma unroll
        for (int mask = 1; mask < 16; mask <<= 1) {
            s += __shfl_xor(s, mask, 64);
            s2 += __shfl_xor(s2, mask, 64);
        }
        if (sl == 0) {
            int rl = g * 4 + j;
            red[(rl * 4 + w) * 2 + 0] = s;
            red[(rl * 4 + w) * 2 + 1] = s2;
        }
    }
    __syncthreads();
#pragma unroll
    for (int j = 0; j < 4; j++) {
        int rl = g * 4 + j;
        float s = 0.f, s2 = 0.f;
#pragma unroll
        for (int i = 0; i < 4; i++) {
            s += red[(rl * 4 + i) * 2 + 0];
            s2 += red[(rl * 4 + i) * 2 + 1];
        }
        float mu = s * (1.f / 512.f);
        float var = s2 * (1.f / 512.f) - mu * mu;
        float inv = rsqrtf(var + LN_EPS);
        float* yp = Y + (size_t)(T0 + rl) * 512;
#pragma unroll
        for (int n = 0; n < 8; n++) {
            int c = w * 128 + n * 16 + sl;
            yp[c] = (acc[n][j] - mu) * inv * gc8[n] + bc8[n];
        }
    }
}

// ---------------------------------------------------------------- launch
extern "C" void kernel_launch(void* const* d_in, const int* in_sizes, int n_in,
                              void* d_out, int out_size, void* d_ws, size_t ws_size,
                              hipStream_t stream) {
    const float* x   = (const float*)d_in[0];
    const float* wq  = (const float*)d_in[1];
    const float* bq  = (const float*)d_in[2];
    const float* wk  = (const float*)d_in[3];
    const float* bk  = (const float*)d_in[4];
    const float* wv  = (const float*)d_in[5];
    const float* bv  = (const float*)d_in[6];
    const float* wo  = (const float*)d_in[7];
    const float* bo  = (const float*)d_in[8];
    const float* lng = (const float*)d_in[9];
    const float* lnb = (const float*)d_in[10];

    char* ws = (char*)d_ws;
    unsigned short* Xb    = (unsigned short*)(ws);                 //  67,108,864  x bf16
    unsigned short* Wqkv  = (unsigned short*)(ws + 67108864);      //   1,572,864  [1536,512] bf16
    unsigned short* Wpack = (unsigned short*)(ws + 68681728);      //     524,288  Wo packed bf16
    float*          Bqkv  = (float*)        (ws + 69206016);       //       6,144  [1536] f32
    unsigned short* QKV   = (unsigned short*)(ws + 69212160);      // 201,326,592  [N,1536] bf16
    float* Y = (float*)d_out;

    cast_x_kernel<<<2048, 256, 0, stream>>>(x, Xb, NTOK * 512 / 8);
    prep_w_kernel<<<1024, 256, 0, stream>>>(wq, wk, wv, wo, bq, bk, bv, Wqkv, Wpack, Bqkv);

    // QKV projection: [65536,512] x [1536,512]^T -> bf16 [65536,1536]
    gemm1_kernel<<<(NTOK / 256) * (QKVN / 256), 512, 0, stream>>>(Xb, Wqkv, Bqkv, QKV);

    // fused: per-token attention + O-proj + bias + residual + LayerNorm -> fp32 d_out
    attn_o_ln_kernel<<<NTOK / 16, 256, 0, stream>>>(QKV, Wpack, bo, x, lng, lnb, Y);
}

// Round 11
// 322.742 us; speedup vs baseline: 1.2715x; 1.0017x over previous
//
#include <hip/hip_runtime.h>
#include <stdint.h>

#define NTOK 65536     // B*S = 16*4096
#define DMODEL 512
#define QKVN 1536
#define LN_EPS 1e-5f

typedef __attribute__((ext_vector_type(8))) short short8;
typedef __attribute__((ext_vector_type(8))) unsigned short ushort8;
typedef __attribute__((ext_vector_type(4))) float float4_t;
typedef __attribute__((ext_vector_type(4))) unsigned int uint4_t;

static __device__ __forceinline__ float bf2f(unsigned short u) {
    union { unsigned int i; float f; } c; c.i = ((unsigned int)u) << 16; return c.f;
}
static __device__ __forceinline__ unsigned short f2bf(float f) {
    union { float f; unsigned int i; } c; c.f = f;
    unsigned int x = c.i;
    return (unsigned short)((x + 0x7fffu + ((x >> 16) & 1u)) >> 16);  // RNE
}
static __device__ __forceinline__ unsigned int cvt_pk_bf16(float lo, float hi) {
    unsigned int r;
    asm("v_cvt_pk_bf16_f32 %0, %1, %2" : "=v"(r) : "v"(lo), "v"(hi));
    return r;
}
static __device__ __forceinline__ void gload_lds16(const void* g, void* l) {
    __builtin_amdgcn_global_load_lds((const __attribute__((address_space(1))) void*)g,
                                     (__attribute__((address_space(3))) void*)l, 16, 0, 0);
}

#define BAR() __builtin_amdgcn_s_barrier()
#define WAITL0() asm volatile("s_waitcnt lgkmcnt(0)" ::: "memory")
#define WVM(n) asm volatile("s_waitcnt vmcnt(" #n ")" ::: "memory")
#define MFMA(a, b, c) __builtin_amdgcn_mfma_f32_16x16x32_bf16((a), (b), (c), 0, 0, 0)

// ---------------------------------------------------------------- prep: cast x to bf16
__global__ __launch_bounds__(256) void cast_x_kernel(const float* __restrict__ x,
                                                     unsigned short* __restrict__ xb, int n8) {
    int stride = gridDim.x * blockDim.x;
    for (int i = blockIdx.x * blockDim.x + threadIdx.x; i < n8; i += stride) {
        const float4_t* p = (const float4_t*)(x + (size_t)i * 8);
        float4_t a = p[0], b = p[1];
        ushort8 v;
        v[0] = f2bf(a[0]); v[1] = f2bf(a[1]); v[2] = f2bf(a[2]); v[3] = f2bf(a[3]);
        v[4] = f2bf(b[0]); v[5] = f2bf(b[1]); v[6] = f2bf(b[2]); v[7] = f2bf(b[3]);
        *(ushort8*)(xb + (size_t)i * 8) = v;
    }
}

// ---------------------------------------------------------------- prep: weights + bias
__global__ __launch_bounds__(256) void prep_w_kernel(
    const float* __restrict__ wq, const float* __restrict__ wk, const float* __restrict__ wv,
    const float* __restrict__ wo,
    const float* __restrict__ bq, const float* __restrict__ bk, const float* __restrict__ bv,
    unsigned short* __restrict__ wqkv, unsigned short* __restrict__ wob,
    float* __restrict__ bias_qkv) {
    const int WN = DMODEL * DMODEL;  // 262144
    int tid = blockIdx.x * blockDim.x + threadIdx.x;
    int stride = gridDim.x * blockDim.x;
    for (int j = tid; j < 3 * WN; j += stride) {
        int seg = j / WN, idx = j - seg * WN;
        const float* src = (seg == 0) ? wq : (seg == 1) ? wk : wv;
        wqkv[j] = f2bf(src[idx]);
    }
    for (int j = tid; j < WN; j += stride) wob[j] = f2bf(wo[j]);
    for (int j = tid; j < QKVN; j += stride)
        bias_qkv[j] = (j < 512) ? bq[j] : (j < 1024) ? bk[j - 512] : bv[j - 1024];
}

// ---------------------------------------------------------------- GEMM1: QKV = Xb @ Wqkv^T + bias
// 256x256 tile, BK=32, 8 waves (2x4), 4-slot circular LDS pipeline (128 KB),
// counted vmcnt (never 0 in steady state), XOR-swizzled LDS, XCD block swizzle.
__global__ __launch_bounds__(512, 2) void gemm1_kernel(
    const unsigned short* __restrict__ A, const unsigned short* __restrict__ Bw,
    const float* __restrict__ bias, unsigned short* __restrict__ Cout) {
    __shared__ unsigned short As[4][256 * 32];  // 64 KB
    __shared__ unsigned short Bs[4][256 * 32];  // 64 KB

    const int b = blockIdx.x;                   // grid = 1536 = 8 * 192
    const int L = (b & 7) * 192 + (b >> 3);     // bijective XCD swizzle
    const int bm = L / 6;
    const int bn = L - bm * 6;

    const int t = threadIdx.x;
    const int lane = t & 63;
    const int w = t >> 6;
    const int wm = w >> 2, wn = w & 3;          // 2 x 4 waves

    const unsigned short* Ab = A + (size_t)bm * 256 * 512;
    const unsigned short* Bb = Bw + (size_t)bn * 256 * 512;

    // staging addressing: LDS linear dest, global source inverse-swizzled
    const int i0 = t, i1 = 512 + t;
    const int r0 = i0 >> 2, s0 = (i0 & 3) ^ ((r0 >> 1) & 3);
    const int r1 = i1 >> 2, s1 = (i1 & 3) ^ ((r1 >> 1) & 3);

#define STAGE_A1(kt) do { \
        gload_lds16(Ab + r0 * 512 + (kt) * 32 + s0 * 8, &As[(kt) & 3][i0 * 8]); \
        gload_lds16(Ab + r1 * 512 + (kt) * 32 + s1 * 8, &As[(kt) & 3][i1 * 8]); } while (0)
#define STAGE_B1(kt) do { \
        gload_lds16(Bb + r0 * 512 + (kt) * 32 + s0 * 8, &Bs[(kt) & 3][i0 * 8]); \
        gload_lds16(Bb + r1 * 512 + (kt) * 32 + s1 * 8, &Bs[(kt) & 3][i1 * 8]); } while (0)

    // fragment read offsets (swizzled): p = (lane>>4) ^ ((row>>1)&3)
    int aoff[8], boff[4];
#pragma unroll
    for (int m = 0; m < 8; m++) {
        int row = wm * 128 + m * 16 + (lane & 15);
        aoff[m] = row * 32 + (((lane >> 4) ^ ((row >> 1) & 3)) * 8);
    }
#pragma unroll
    for (int n = 0; n < 4; n++) {
        int row = wn * 64 + n * 16 + (lane & 15);
        boff[n] = row * 32 + (((lane >> 4) ^ ((row >> 1) & 3)) * 8);
    }

    float4_t acc[8][4];
#pragma unroll
    for (int m = 0; m < 8; m++)
#pragma unroll
        for (int n = 0; n < 4; n++) acc[m][n] = (float4_t){0.f, 0.f, 0.f, 0.f};

    // prologue: stage K-tiles 0,1,2 (12 loads); wait tile 0 (8 remain in flight)
    STAGE_A1(0); STAGE_B1(0);
    STAGE_A1(1); STAGE_B1(1);
    STAGE_A1(2); STAGE_B1(2);
    WVM(8);
    BAR();

    short8 ar[8], br[4];
#pragma unroll
    for (int kt = 0; kt < 16; ++kt) {
        const int sl = kt & 3;
        // ---- phase 0: read A frags + B n0/n1, stage A of kt+3, MFMA n-half 0
#pragma unroll
        for (int m = 0; m < 8; m++) ar[m] = *(const short8*)&As[sl][aoff[m]];
        br[0] = *(const short8*)&Bs[sl][boff[0]];
        br[1] = *(const short8*)&Bs[sl][boff[1]];
        if (kt <= 12) STAGE_A1(kt + 3);
        BAR();
        WAITL0();
        __builtin_amdgcn_s_setprio(1);
#pragma unroll
        for (int m = 0; m < 8; m++) {
            acc[m][0] = MFMA(ar[m], br[0], acc[m][0]);
            acc[m][1] = MFMA(ar[m], br[1], acc[m][1]);
        }
        __builtin_amdgcn_s_setprio(0);
        BAR();
        // ---- phase 1: read B n2/n3, stage B of kt+3, MFMA n-half 1
        br[2] = *(const short8*)&Bs[sl][boff[2]];
        br[3] = *(const short8*)&Bs[sl][boff[3]];
        if (kt <= 12) STAGE_B1(kt + 3);
        BAR();
        WAITL0();
        __builtin_amdgcn_s_setprio(1);
#pragma unroll
        for (int m = 0; m < 8; m++) {
            acc[m][2] = MFMA(ar[m], br[2], acc[m][2]);
            acc[m][3] = MFMA(ar[m], br[3], acc[m][3]);
        }
        __builtin_amdgcn_s_setprio(0);
        // K-tile boundary: ensure tile kt+1 landed; keep 2 tiles (8 loads) in flight
        if (kt <= 12) { WVM(8); }
        else if (kt == 13) { WVM(4); }
        else if (kt == 14) { WVM(0); }
        BAR();
    }

    // ---- epilogue: C/D mapping col=lane&15, row=(lane>>4)*4+j
    const int orow0 = bm * 256 + wm * 128;
    const int ocol0 = bn * 256 + wn * 64;
#pragma unroll
    for (int m = 0; m < 8; m++) {
#pragma unroll
        for (int n = 0; n < 4; n++) {
            int col = ocol0 + n * 16 + (lane & 15);
            float bv = bias[col];
#pragma unroll
            for (int j = 0; j < 4; j++) {
                int row = orow0 + m * 16 + (lane >> 4) * 4 + j;
                Cout[(size_t)row * QKVN + col] = f2bf(acc[m][n][j] + bv);
            }
        }
    }
#undef STAGE_A1
#undef STAGE_B1
}

// ---------------------------------------------------------------- FUSED v2: attention + O-proj + residual + LN
// Block = 64 tokens, 512 threads = 8 waves. 128 KB LDS, 1 block/CU, 256-reg budget.
// Phase 1: attention (8 tokens/wave, QKV loaded once per round), AO -> swizzled
//          64 KB LDS A-tile.  B-tile 0 staged BEFORE phase 1 (streams under VALU).
// Phase 2: gemm1-style 2-slot counted-vmcnt B pipeline (Wo row-major, 4 gload/thread),
//          wave = 2 m-frags x 8 n-frags (acc 64 regs).
// Epilogue: bias + resid + full-row LN (red overlay on B slots).
__global__ __launch_bounds__(512, 2) void attn_gemm_ln_kernel(
    const unsigned short* __restrict__ qkv, const unsigned short* __restrict__ Wob,
    const float* __restrict__ bo, const float* __restrict__ xres,
    const float* __restrict__ lng, const float* __restrict__ lnb,
    float* __restrict__ Y) {
    __shared__ __align__(16) unsigned char AOs[64 * 1024];    // 64 KB: 64 rows x 512 bf16, swizzled
    __shared__ __align__(16) unsigned char Bsm[2][32768];     // 64 KB: 2 slots of 512x32 bf16
    float* red = (float*)Bsm;                                 // epilogue overlay (2 KB)

    const int T0 = blockIdx.x * 64;
    const int t = threadIdx.x;
    const int lane = t & 63;
    const int w = t >> 6;        // 0..7
    const int g = lane >> 4;     // 0..3
    const int sl = lane & 15;    // 0..15
    const int wm = w >> 2;       // m-half: rows wm*32..+31
    const int wn = w & 3;        // n-quarter: cols wn*128..+127

    // B staging: 4 x 16B per thread per K-tile; LDS linear, source inverse-swizzled
#define STAGE_B2(kt) do { \
        _Pragma("unroll") \
        for (int c = 0; c < 4; c++) { \
            int idx = c * 512 + t; \
            int row = idx >> 2; \
            int s = (idx & 3) ^ ((row >> 1) & 3); \
            gload_lds16(Wob + row * 512 + (kt) * 32 + s * 8, &Bsm[(kt) & 1][idx * 16]); \
        } } while (0)

    STAGE_B2(0);  // issue early: lands while attention runs

    // ---------------- phase 1: attention, 8 tokens/wave (2 rounds x 4)
    const float scale = 0.08838834764831845f;  // 1/sqrt(128)
#pragma unroll
    for (int r = 0; r < 2; ++r) {
        const int tr = w * 8 + r * 4 + g;  // 0..63
        const unsigned short* base = qkv + (size_t)(T0 + tr) * QKVN + sl * 8;

        short8 qr[4], kr[4], vr[4];
#pragma unroll
        for (int h = 0; h < 4; h++) {
            qr[h] = *(const short8*)(base + h * 128);
            kr[h] = *(const short8*)(base + 512 + h * 128);
            vr[h] = *(const short8*)(base + 1024 + h * 128);
        }
#pragma unroll
        for (int h = 0; h < 4; h++) {
            float qf[8];
#pragma unroll
            for (int d = 0; d < 8; d++) qf[d] = bf2f((unsigned short)qr[h][d]);
            float s[4];
#pragma unroll
            for (int tt = 0; tt < 4; tt++) {
                float a0 = 0.f;
#pragma unroll
                for (int d = 0; d < 8; d++) a0 += qf[d] * bf2f((unsigned short)kr[tt][d]);
                s[tt] = a0;
            }
#pragma unroll
            for (int mask = 1; mask < 16; mask <<= 1)
#pragma unroll
                for (int tt = 0; tt < 4; tt++)
                    s[tt] += __shfl_xor(s[tt], mask, 64);
            float m0 = fmaxf(fmaxf(s[0], s[1]), fmaxf(s[2], s[3])) * scale;
            float p[4];
            float sum = 0.f;
#pragma unroll
            for (int tt = 0; tt < 4; tt++) { p[tt] = __expf(s[tt] * scale - m0); sum += p[tt]; }
            float rr = __frcp_rn(sum);
            float o[8];
#pragma unroll
            for (int d = 0; d < 8; d++) o[d] = 0.f;
#pragma unroll
            for (int tt = 0; tt < 4; tt++) {
                float ph = p[tt] * rr;
#pragma unroll
                for (int d = 0; d < 8; d++) o[d] += ph * bf2f((unsigned short)vr[tt][d]);
            }
            uint4_t pk;
            pk[0] = cvt_pk_bf16(o[0], o[1]);
            pk[1] = cvt_pk_bf16(o[2], o[3]);
            pk[2] = cvt_pk_bf16(o[4], o[5]);
            pk[3] = cvt_pk_bf16(o[6], o[7]);
            int off = tr * 1024 + ((h * 256 + sl * 16) ^ ((tr & 7) << 4));
            *(uint4_t*)(AOs + off) = pk;
        }
    }
    __syncthreads();  // A-tile complete & visible (drains lgkmcnt)

    // ---------------- phase 2: [64x512] = AOs @ Wo^T, counted-vmcnt B pipeline
    const int arow0 = wm * 32 + sl;         // m-frag 0 row
    const int arow1 = wm * 32 + 16 + sl;    // m-frag 1 row
    const int aswz0 = (arow0 & 7) << 4;
    const int aswz1 = (arow1 & 7) << 4;
    int boffB[8];
#pragma unroll
    for (int n = 0; n < 8; n++) {
        int row = wn * 128 + n * 16 + sl;
        boffB[n] = row * 64 + ((g ^ ((row >> 1) & 3)) * 16);
    }

    float4_t acc[2][8];
#pragma unroll
    for (int m = 0; m < 2; m++)
#pragma unroll
        for (int n = 0; n < 8; n++) acc[m][n] = (float4_t){0.f, 0.f, 0.f, 0.f};

#pragma unroll 1
    for (int kt = 0; kt < 16; ++kt) {
        if (kt < 15) { STAGE_B2(kt + 1); WVM(4); }
        else { WVM(0); }
        BAR();
        const unsigned char* Bp = Bsm[kt & 1];
        short8 a0 = *(const short8*)(AOs + arow0 * 1024 + ((kt * 64 + g * 16) ^ aswz0));
        short8 a1 = *(const short8*)(AOs + arow1 * 1024 + ((kt * 64 + g * 16) ^ aswz1));
        __builtin_amdgcn_s_setprio(1);
#pragma unroll
        for (int n = 0; n < 8; n++) {
            short8 bf = *(const short8*)(Bp + boffB[n]);
            acc[0][n] = MFMA(a0, bf, acc[0][n]);
            acc[1][n] = MFMA(a1, bf, acc[1][n]);
        }
        __builtin_amdgcn_s_setprio(0);
        BAR();  // all reads of slot kt&1 done before it is restaged
    }
    __syncthreads();  // safe to overlay red on Bsm

    // ---------------- epilogue: bias + residual, LN over the 512-col row, fp32 out
    float bias8[8], gc8[8], bc8[8];
#pragma unroll
    for (int n = 0; n < 8; n++) {
        int c = wn * 128 + n * 16 + sl;
        bias8[n] = bo[c]; gc8[n] = lng[c]; bc8[n] = lnb[c];
    }
#pragma unroll
    for (int m = 0; m < 2; m++) {
#pragma unroll
        for (int j = 0; j < 4; j++) {
            int grow = T0 + wm * 32 + m * 16 + g * 4 + j;
            const float* xr = xres + (size_t)grow * 512;
#pragma unroll
            for (int n = 0; n < 8; n++)
                acc[m][n][j] += bias8[n] + xr[wn * 128 + n * 16 + sl];
        }
    }
    // per-row partials over this wave's 128 cols; 16-lane butterfly; red[rl][wn]
#pragma unroll
    for (int m = 0; m < 2; m++) {
#pragma unroll
        for (int j = 0; j < 4; j++) {
            float s = 0.f, s2 = 0.f;
#pragma unroll
            for (int n = 0; n < 8; n++) { float v = acc[m][n][j]; s += v; s2 += v * v; }
#pragma unroll
            for (int mask = 1; mask < 16; mask <<= 1) {
                s += __shfl_xor(s, mask, 64);
                s2 += __shfl_xor(s2, mask, 64);
            }
            if (sl == 0) {
                int rl = wm * 32 + m * 16 + g * 4 + j;
                red[(rl * 4 + wn) * 2 + 0] = s;
                red[(rl * 4 + wn) * 2 + 1] = s2;
            }
        }
    }
    __syncthreads();
#pragma unroll
    for (int m = 0; m < 2; m++) {
#pragma unroll
        for (int j = 0; j < 4; j++) {
            int rl = wm * 32 + m * 16 + g * 4 + j;
            float s = 0.f, s2 = 0.f;
#pragma unroll
            for (int i = 0; i < 4; i++) {
                s += red[(rl * 4 + i) * 2 + 0];
                s2 += red[(rl * 4 + i) * 2 + 1];
            }
            float mu = s * (1.f / 512.f);
            float var = s2 * (1.f / 512.f) - mu * mu;
            float inv = rsqrtf(var + LN_EPS);
            float* yp = Y + (size_t)(T0 + rl) * 512;
#pragma unroll
            for (int n = 0; n < 8; n++) {
                int c = wn * 128 + n * 16 + sl;
                yp[c] = (acc[m][n][j] - mu) * inv * gc8[n] + bc8[n];
            }
        }
    }
#undef STAGE_B2
}

// ---------------------------------------------------------------- launch
extern "C" void kernel_launch(void* const* d_in, const int* in_sizes, int n_in,
                              void* d_out, int out_size, void* d_ws, size_t ws_size,
                              hipStream_t stream) {
    const float* x   = (const float*)d_in[0];
    const float* wq  = (const float*)d_in[1];
    const float* bq  = (const float*)d_in[2];
    const float* wk  = (const float*)d_in[3];
    const float* bk  = (const float*)d_in[4];
    const float* wv  = (const float*)d_in[5];
    const float* bv  = (const float*)d_in[6];
    const float* wo  = (const float*)d_in[7];
    const float* bo  = (const float*)d_in[8];
    const float* lng = (const float*)d_in[9];
    const float* lnb = (const float*)d_in[10];

    char* ws = (char*)d_ws;
    unsigned short* Xb    = (unsigned short*)(ws);                 //  67,108,864  x bf16
    unsigned short* Wqkv  = (unsigned short*)(ws + 67108864);      //   1,572,864  [1536,512] bf16
    unsigned short* Wob   = (unsigned short*)(ws + 68681728);      //     524,288  [512,512] bf16 row-major
    float*          Bqkv  = (float*)        (ws + 69206016);       //       6,144  [1536] f32
    unsigned short* QKV   = (unsigned short*)(ws + 69212160);      // 201,326,592  [N,1536] bf16
    float* Y = (float*)d_out;

    cast_x_kernel<<<2048, 256, 0, stream>>>(x, Xb, NTOK * 512 / 8);
    prep_w_kernel<<<1024, 256, 0, stream>>>(wq, wk, wv, wo, bq, bk, bv, Wqkv, Wob, Bqkv);

    // QKV projection: [65536,512] x [1536,512]^T -> bf16 [65536,1536]
    gemm1_kernel<<<(NTOK / 256) * (QKVN / 256), 512, 0, stream>>>(Xb, Wqkv, Bqkv, QKV);

    // fused: per-token attention + O-proj + bias + residual + LayerNorm -> fp32 d_out
    attn_gemm_ln_kernel<<<NTOK / 64, 512, 0, stream>>>(QKV, Wob, bo, x, lng, lnb, Y);
}